// Round 1
// baseline (13182.808 us; speedup 1.0000x reference)
//
#include <hip/hip_runtime.h>
#include <hip/hip_bf16.h>
#include <math.h>

#define D_MODEL 768
#define N_LAYER 8
#define D_STATE 128
#define D_CONV 4
#define HEADDIM 64
#define D_INNER 1536
#define NHEADS 24
#define D_IN_PROJ 3352   // 2*D_INNER + 2*D_STATE + NHEADS
#define CONV_DIM 1792    // D_INNER + 2*D_STATE
#define SEQLEN 1024
#define VOCAB 50288
#define EPS 1e-5f

// ---------------- embedding gather ----------------
__global__ void k_embed(const int* __restrict__ ids, const float* __restrict__ emb,
                        float* __restrict__ x) {
    int t = blockIdx.x;
    int id = ids[t];
    const float* er = emb + (long)id * D_MODEL;
    for (int d = threadIdx.x; d < D_MODEL; d += blockDim.x)
        x[(long)t * D_MODEL + d] = er[d];
}

// ---------------- LUT rmsnorm (768) ----------------
__global__ void k_lutnorm(const float* __restrict__ x, const float* __restrict__ w,
                          float* __restrict__ out) {
    __shared__ float sbuf[256];
    int t = blockIdx.x;
    const float* xr = x + (long)t * D_MODEL;
    float ss = 0.f;
    for (int d = threadIdx.x; d < D_MODEL; d += 256) { float v = xr[d]; ss += v * v; }
    sbuf[threadIdx.x] = ss; __syncthreads();
    for (int s = 128; s > 0; s >>= 1) {
        if (threadIdx.x < s) sbuf[threadIdx.x] += sbuf[threadIdx.x + s];
        __syncthreads();
    }
    float rms = sbuf[0] / (float)D_MODEL + EPS;
    const float X0 = 1e-5f;
    const float STEP = (10.0f - 1e-5f) / 255.0f;
    int idx = (int)ceilf((rms - X0) / STEP);
    idx = min(max(idx, 0), 255);
    // fixup: want smallest idx with LUT_X[idx] >= rms (searchsorted 'left'), clipped 0..255
    while (idx > 0 && (X0 + (float)(idx - 1) * STEP) >= rms) --idx;
    while (idx < 255 && (X0 + (float)idx * STEP) < rms) ++idx;
    float scale = 1.0f / sqrtf(X0 + (float)idx * STEP);
    for (int d = threadIdx.x; d < D_MODEL; d += 256)
        out[(long)t * D_MODEL + d] = xr[d] * scale * w[d];
}

// ---------------- generic fp32 GEMM: C[M,N] (+)= A[M,K] * B[N,K]^T ----------------
template <bool ACC>
__global__ __launch_bounds__(256) void k_gemm(const float* __restrict__ A,
                                              const float* __restrict__ B,
                                              float* __restrict__ C,
                                              int M, int N, int K) {
    __shared__ float As[16][64];
    __shared__ float Bs[16][65];
    int bm = blockIdx.x * 64, bn = blockIdx.y * 64;
    int tid = threadIdx.x;
    int tx = tid & 15, ty = tid >> 4;
    int lr = tid >> 2;          // 0..63
    int lk = (tid & 3) * 4;     // 0,4,8,12
    float acc[4][4] = {};
    for (int k0 = 0; k0 < K; k0 += 16) {
        float4 av = *(const float4*)(A + (long)(bm + lr) * K + k0 + lk);
        As[lk + 0][lr] = av.x; As[lk + 1][lr] = av.y;
        As[lk + 2][lr] = av.z; As[lk + 3][lr] = av.w;
        int bn_r = bn + lr;
        float4 bv = make_float4(0.f, 0.f, 0.f, 0.f);
        if (bn_r < N) bv = *(const float4*)(B + (long)bn_r * K + k0 + lk);
        Bs[lk + 0][lr] = bv.x; Bs[lk + 1][lr] = bv.y;
        Bs[lk + 2][lr] = bv.z; Bs[lk + 3][lr] = bv.w;
        __syncthreads();
#pragma unroll
        for (int kk = 0; kk < 16; ++kk) {
            float a[4], b[4];
#pragma unroll
            for (int i = 0; i < 4; ++i) a[i] = As[kk][ty * 4 + i];
#pragma unroll
            for (int j = 0; j < 4; ++j) b[j] = Bs[kk][tx * 4 + j];
#pragma unroll
            for (int i = 0; i < 4; ++i)
#pragma unroll
                for (int j = 0; j < 4; ++j)
                    acc[i][j] = fmaf(a[i], b[j], acc[i][j]);
        }
        __syncthreads();
    }
#pragma unroll
    for (int i = 0; i < 4; ++i) {
        int m = bm + ty * 4 + i;
#pragma unroll
        for (int j = 0; j < 4; ++j) {
            int n = bn + tx * 4 + j;
            if (n < N) {
                long off = (long)m * N + n;
                if (ACC) C[off] += acc[i][j]; else C[off] = acc[i][j];
            }
        }
    }
}

// ---------------- activation quant ----------------
__global__ void k_zero(unsigned* p) { *p = 0u; }

__global__ void k_absmax(const float* __restrict__ zx, unsigned* __restrict__ out) {
    __shared__ float sbuf[256];
    float m = 0.f;
    int total = SEQLEN * CONV_DIM;
    for (int i = blockIdx.x * blockDim.x + threadIdx.x; i < total; i += gridDim.x * blockDim.x) {
        int t = i / CONV_DIM, c = i - t * CONV_DIM;
        float v = fabsf(zx[(long)t * D_IN_PROJ + D_INNER + c]);
        m = fmaxf(m, v);
    }
    sbuf[threadIdx.x] = m; __syncthreads();
    for (int s = 128; s > 0; s >>= 1) {
        if (threadIdx.x < s) sbuf[threadIdx.x] = fmaxf(sbuf[threadIdx.x], sbuf[threadIdx.x + s]);
        __syncthreads();
    }
    if (threadIdx.x == 0) atomicMax(out, __float_as_uint(sbuf[0]));
}

__global__ void k_quant(const float* __restrict__ zx, const unsigned* __restrict__ mx,
                        float* __restrict__ xq) {
    int i = blockIdx.x * blockDim.x + threadIdx.x;
    if (i >= SEQLEN * CONV_DIM) return;
    float s = __uint_as_float(*mx) / (127.0f + 1e-8f);
    int t = i / CONV_DIM, c = i - t * CONV_DIM;
    float v = rintf(zx[(long)t * D_IN_PROJ + D_INNER + c] / s);
    xq[i] = fminf(fmaxf(v, -128.0f), 127.0f);
}

// ---------------- depthwise conv (quantized, zp-not-subtracted like ref) + silu ----------------
__global__ void k_conv(const float* __restrict__ xq, const float* __restrict__ qcw,
                       const float* __restrict__ cb, const float* __restrict__ cscale,
                       const unsigned* __restrict__ mx, float* __restrict__ xact) {
    int i = blockIdx.x * blockDim.x + threadIdx.x;
    if (i >= SEQLEN * CONV_DIM) return;
    float s = __uint_as_float(*mx) / (127.0f + 1e-8f);
    int t = i / CONV_DIM, c = i - t * CONV_DIM;
    float acc = cb[c];
#pragma unroll
    for (int k = 0; k < D_CONV; ++k) {
        int tt = t - (D_CONV - 1) + k;
        if (tt >= 0) acc = fmaf(xq[(long)tt * CONV_DIM + c], qcw[c * D_CONV + k], acc);
    }
    float v = acc * (cscale[0] * s);
    xact[i] = v / (1.0f + expf(-v));
}

// ---------------- dt = softplus(raw + bias) ----------------
__global__ void k_dt(const float* __restrict__ zx, const float* __restrict__ dt_bias,
                     float* __restrict__ dt) {
    int i = blockIdx.x * blockDim.x + threadIdx.x;
    if (i >= SEQLEN * NHEADS) return;
    int t = i / NHEADS, h = i - t * NHEADS;
    float v = zx[(long)t * D_IN_PROJ + (D_INNER + CONV_DIM) + h] + dt_bias[h];
    dt[i] = fmaxf(v, 0.0f) + log1pf(expf(-fabsf(v)));
}

// ---------------- sequential SSM scan: 1 block per head, state in registers ----------------
__global__ __launch_bounds__(256) void k_scan(const float* __restrict__ xact,
                                              const float* __restrict__ dtbuf,
                                              const float* __restrict__ A_log,
                                              const float* __restrict__ D_param,
                                              float* __restrict__ y) {
    int head = blockIdx.x;
    int tid = threadIdx.x;
    int p = tid & 63;          // headdim row
    int w = tid >> 6;          // wave = n-chunk
    float negA = -expf(A_log[head]);
    float Dp = D_param[head];
    float h[32];
#pragma unroll
    for (int j = 0; j < 32; ++j) h[j] = 0.f;
    __shared__ float BC[256];      // B: [0..127], C: [128..255]
    __shared__ float part[4][64];
    for (int t = 0; t < SEQLEN; ++t) {
        const float* row = xact + (long)t * CONV_DIM;
        BC[tid] = row[D_INNER + tid];     // cols 1536..1791 = B then C
        __syncthreads();
        float dtv = dtbuf[t * NHEADS + head];
        float a = expf(dtv * negA);
        float xv = row[head * HEADDIM + p];
        float xdt = xv * dtv;
        float acc = 0.f;
#pragma unroll
        for (int j = 0; j < 32; ++j) {
            int n = w * 32 + j;
            h[j] = fmaf(a, h[j], xdt * BC[n]);
            acc = fmaf(h[j], BC[128 + n], acc);
        }
        part[w][p] = acc;
        __syncthreads();
        if (tid < 64) {
            y[(long)t * D_INNER + head * HEADDIM + p] =
                part[0][p] + part[1][p] + part[2][p] + part[3][p] + xv * Dp;
        }
    }
}

// ---------------- gate (y * silu(z)) + rmsnorm(1536) ----------------
__global__ void k_gatenorm(const float* __restrict__ ybuf, const float* __restrict__ zx,
                           const float* __restrict__ mnw, float* __restrict__ y3) {
    __shared__ float sbuf[256];
    int t = blockIdx.x;
    const float* yr = ybuf + (long)t * D_INNER;
    const float* zr = zx + (long)t * D_IN_PROJ;
    float vals[6];
    float ss = 0.f;
#pragma unroll
    for (int j = 0; j < 6; ++j) {
        int e = threadIdx.x + j * 256;
        float z = zr[e];
        float v = yr[e] * (z / (1.0f + expf(-z)));
        vals[j] = v; ss += v * v;
    }
    sbuf[threadIdx.x] = ss; __syncthreads();
    for (int s = 128; s > 0; s >>= 1) {
        if (threadIdx.x < s) sbuf[threadIdx.x] += sbuf[threadIdx.x + s];
        __syncthreads();
    }
    float scale = 1.0f / sqrtf(sbuf[0] / (float)D_INNER + EPS);
#pragma unroll
    for (int j = 0; j < 6; ++j) {
        int e = threadIdx.x + j * 256;
        y3[(long)t * D_INNER + e] = vals[j] * scale * mnw[e];
    }
}

extern "C" void kernel_launch(void* const* d_in, const int* in_sizes, int n_in,
                              void* d_out, int out_size, void* d_ws, size_t ws_size,
                              hipStream_t stream) {
    const int*   ids    = (const int*)d_in[0];
    const float* emb    = (const float*)d_in[1];
    const float* norm_w = (const float*)d_in[2];
    const float* inw    = (const float*)d_in[3];
    const float* qconv  = (const float*)d_in[4];
    const float* cscale = (const float*)d_in[5];
    const float* convb  = (const float*)d_in[6];
    const float* dtbias = (const float*)d_in[7];
    const float* alog   = (const float*)d_in[8];
    const float* dpar   = (const float*)d_in[9];
    const float* mnw    = (const float*)d_in[10];
    const float* outw   = (const float*)d_in[11];
    const float* normf  = (const float*)d_in[12];
    const float* lmw    = (const float*)d_in[13];
    float* out = (float*)d_out;

    float* p = (float*)d_ws;
    float* xres = p; p += (long)SEQLEN * D_MODEL;
    float* u    = p; p += (long)SEQLEN * D_MODEL;
    float* zx   = p; p += (long)SEQLEN * D_IN_PROJ;
    float* xq   = p; p += (long)SEQLEN * CONV_DIM;
    float* xact = p; p += (long)SEQLEN * CONV_DIM;
    float* dtb  = p; p += (long)SEQLEN * NHEADS;
    float* ybuf = p; p += (long)SEQLEN * D_INNER;
    float* y3   = p; p += (long)SEQLEN * D_INNER;
    unsigned* mx = (unsigned*)p;

    k_embed<<<SEQLEN, 256, 0, stream>>>(ids, emb, xres);

    int nq = SEQLEN * CONV_DIM;
    int nd = SEQLEN * NHEADS;
    for (int l = 0; l < N_LAYER; ++l) {
        k_lutnorm<<<SEQLEN, 256, 0, stream>>>(xres, norm_w + l * D_MODEL, u);
        dim3 g1(SEQLEN / 64, (D_IN_PROJ + 63) / 64);
        k_gemm<false><<<g1, 256, 0, stream>>>(u, inw + (long)l * D_IN_PROJ * D_MODEL, zx,
                                              SEQLEN, D_IN_PROJ, D_MODEL);
        k_zero<<<1, 1, 0, stream>>>(mx);
        k_absmax<<<256, 256, 0, stream>>>(zx, mx);
        k_quant<<<(nq + 255) / 256, 256, 0, stream>>>(zx, mx, xq);
        k_conv<<<(nq + 255) / 256, 256, 0, stream>>>(xq, qconv + l * CONV_DIM * D_CONV,
                                                     convb + l * CONV_DIM, cscale + l, mx, xact);
        k_dt<<<(nd + 255) / 256, 256, 0, stream>>>(zx, dtbias + l * NHEADS, dtb);
        k_scan<<<NHEADS, 256, 0, stream>>>(xact, dtb, alog + l * NHEADS, dpar + l * NHEADS, ybuf);
        k_gatenorm<<<SEQLEN, 256, 0, stream>>>(ybuf, zx, mnw + l * D_INNER, y3);
        dim3 g2(SEQLEN / 64, (D_MODEL + 63) / 64);
        k_gemm<true><<<g2, 256, 0, stream>>>(y3, outw + (long)l * D_MODEL * D_INNER, xres,
                                             SEQLEN, D_MODEL, D_INNER);
    }
    k_lutnorm<<<SEQLEN, 256, 0, stream>>>(xres, normf, u);
    dim3 g3(SEQLEN / 64, (VOCAB + 63) / 64);
    k_gemm<false><<<g3, 256, 0, stream>>>(u, lmw, out, SEQLEN, VOCAB, D_MODEL);
}

// Round 3
// 4375.331 us; speedup vs baseline: 3.0130x; 3.0130x over previous
//
#include <hip/hip_runtime.h>
#include <math.h>

#define D_MODEL 768
#define N_LAYER 8
#define D_STATE 128
#define D_CONV 4
#define HEADDIM 64
#define D_INNER 1536
#define NHEADS 24
#define D_IN_PROJ 3352   // 2*D_INNER + 2*D_STATE + NHEADS
#define CONV_DIM 1792    // D_INNER + 2*D_STATE
#define SEQLEN 1024
#define VOCAB 50288
#define EPS 1e-5f

typedef __bf16 bf16x8 __attribute__((ext_vector_type(8)));
typedef float f32x4 __attribute__((ext_vector_type(4)));

__device__ inline unsigned short f2bf(float x) {
    union { float f; unsigned u; } v; v.f = x;
    unsigned r = v.u + 0x7fffu + ((v.u >> 16) & 1u);
    return (unsigned short)(r >> 16);
}
__device__ inline float bf2f(unsigned short b) {
    union { unsigned u; float f; } v; v.u = ((unsigned)b) << 16;
    return v.f;
}

// ---------------- embedding gather ----------------
__global__ void k_embed(const int* __restrict__ ids, const float* __restrict__ emb,
                        float* __restrict__ x) {
    int t = blockIdx.x;
    int id = ids[t];
    const float* er = emb + (long)id * D_MODEL;
    for (int d = threadIdx.x; d < D_MODEL; d += blockDim.x)
        x[(long)t * D_MODEL + d] = er[d];
}

// ---------------- LUT rmsnorm (768) ----------------
__global__ void k_lutnorm(const float* __restrict__ x, const float* __restrict__ w,
                          float* __restrict__ out) {
    __shared__ float sbuf[256];
    int t = blockIdx.x;
    const float* xr = x + (long)t * D_MODEL;
    float ss = 0.f;
    for (int d = threadIdx.x; d < D_MODEL; d += 256) { float v = xr[d]; ss += v * v; }
    sbuf[threadIdx.x] = ss; __syncthreads();
    for (int s = 128; s > 0; s >>= 1) {
        if (threadIdx.x < s) sbuf[threadIdx.x] += sbuf[threadIdx.x + s];
        __syncthreads();
    }
    float rms = sbuf[0] / (float)D_MODEL + EPS;
    const float X0 = 1e-5f;
    const float STEP = (10.0f - 1e-5f) / 255.0f;
    int idx = (int)ceilf((rms - X0) / STEP);
    idx = min(max(idx, 0), 255);
    while (idx > 0 && (X0 + (float)(idx - 1) * STEP) >= rms) --idx;
    while (idx < 255 && (X0 + (float)idx * STEP) < rms) ++idx;
    float scale = 1.0f / sqrtf(X0 + (float)idx * STEP);
    for (int d = threadIdx.x; d < D_MODEL; d += 256)
        out[(long)t * D_MODEL + d] = xr[d] * scale * w[d];
}

// ---------------- MFMA GEMM: C[M,N] (+)= A[M,K] * B[N,K]^T ----------------
// PASSES=1: plain bf16.  PASSES=3: bf16x2 split (hi*hi + lo*hi + hi*lo) ~ fp32 accuracy.
// LDS fragment-major layout [granule][row][8] -> conflict-free ds_read_b128.
template <int PASSES, bool ACCUM>
__global__ __launch_bounds__(256) void k_gemm_mfma(const float* __restrict__ A,
                                                   const float* __restrict__ B,
                                                   float* __restrict__ C,
                                                   int M, int N, int K) {
    __shared__ __align__(16) unsigned short Ah[4][128][8];
    __shared__ __align__(16) unsigned short Bh[4][128][8];
    __shared__ __align__(16) unsigned short Al[(PASSES == 3) ? 4 : 1][128][8];
    __shared__ __align__(16) unsigned short Bl[(PASSES == 3) ? 4 : 1][128][8];

    const int bm = blockIdx.x * 128, bn = blockIdx.y * 128;
    const int tid = threadIdx.x;
    const int rr = tid >> 2, g = tid & 3;     // staging: row 0..63(+64), k-granule
    const int w = tid >> 6, l = tid & 63;
    const int wm = w >> 1, wn = w & 1;        // 2x2 waves, 64x64 each
    const int lr = l & 15, lg = l >> 4;

    f32x4 acc[4][4];
#pragma unroll
    for (int m = 0; m < 4; ++m)
#pragma unroll
        for (int n = 0; n < 4; ++n) acc[m][n] = (f32x4){0.f, 0.f, 0.f, 0.f};

    for (int k0 = 0; k0 < K; k0 += 32) {
#pragma unroll
        for (int half = 0; half < 2; ++half) {
            int r = rr + half * 64;
            // A tile (always in-bounds: M % 128 == 0)
            {
                const float* s = A + (size_t)(bm + r) * K + k0 + g * 8;
                float4 f0 = *(const float4*)s;
                float4 f1 = *(const float4*)(s + 4);
                float ff[8] = {f0.x, f0.y, f0.z, f0.w, f1.x, f1.y, f1.z, f1.w};
                unsigned short h[8], lo[8];
#pragma unroll
                for (int i = 0; i < 8; ++i) {
                    h[i] = f2bf(ff[i]);
                    if (PASSES == 3) lo[i] = f2bf(ff[i] - bf2f(h[i]));
                }
                uint4 uh = make_uint4(h[0] | (h[1] << 16), h[2] | (h[3] << 16),
                                      h[4] | (h[5] << 16), h[6] | (h[7] << 16));
                *(uint4*)&Ah[g][r][0] = uh;
                if (PASSES == 3) {
                    uint4 ul = make_uint4(lo[0] | (lo[1] << 16), lo[2] | (lo[3] << 16),
                                          lo[4] | (lo[5] << 16), lo[6] | (lo[7] << 16));
                    *(uint4*)&Al[g][r][0] = ul;
                }
            }
            // B tile (bounds on N)
            {
                int rB = bn + r;
                float ff[8] = {0.f, 0.f, 0.f, 0.f, 0.f, 0.f, 0.f, 0.f};
                if (rB < N) {
                    const float* s = B + (size_t)rB * K + k0 + g * 8;
                    float4 f0 = *(const float4*)s;
                    float4 f1 = *(const float4*)(s + 4);
                    ff[0] = f0.x; ff[1] = f0.y; ff[2] = f0.z; ff[3] = f0.w;
                    ff[4] = f1.x; ff[5] = f1.y; ff[6] = f1.z; ff[7] = f1.w;
                }
                unsigned short h[8], lo[8];
#pragma unroll
                for (int i = 0; i < 8; ++i) {
                    h[i] = f2bf(ff[i]);
                    if (PASSES == 3) lo[i] = f2bf(ff[i] - bf2f(h[i]));
                }
                uint4 uh = make_uint4(h[0] | (h[1] << 16), h[2] | (h[3] << 16),
                                      h[4] | (h[5] << 16), h[6] | (h[7] << 16));
                *(uint4*)&Bh[g][r][0] = uh;
                if (PASSES == 3) {
                    uint4 ul = make_uint4(lo[0] | (lo[1] << 16), lo[2] | (lo[3] << 16),
                                          lo[4] | (lo[5] << 16), lo[6] | (lo[7] << 16));
                    *(uint4*)&Bl[g][r][0] = ul;
                }
            }
        }
        __syncthreads();

        bf16x8 ah[4], bh[4], al_[4], bl_[4];
#pragma unroll
        for (int m = 0; m < 4; ++m) {
            int row = wm * 64 + m * 16 + lr;
            ah[m] = *(const bf16x8*)&Ah[lg][row][0];
            if (PASSES == 3) al_[m] = *(const bf16x8*)&Al[lg][row][0];
        }
#pragma unroll
        for (int n = 0; n < 4; ++n) {
            int row = wn * 64 + n * 16 + lr;
            bh[n] = *(const bf16x8*)&Bh[lg][row][0];
            if (PASSES == 3) bl_[n] = *(const bf16x8*)&Bl[lg][row][0];
        }
#pragma unroll
        for (int m = 0; m < 4; ++m)
#pragma unroll
            for (int n = 0; n < 4; ++n) {
                acc[m][n] = __builtin_amdgcn_mfma_f32_16x16x32_bf16(ah[m], bh[n], acc[m][n], 0, 0, 0);
                if (PASSES == 3) {
                    acc[m][n] = __builtin_amdgcn_mfma_f32_16x16x32_bf16(al_[m], bh[n], acc[m][n], 0, 0, 0);
                    acc[m][n] = __builtin_amdgcn_mfma_f32_16x16x32_bf16(ah[m], bl_[n], acc[m][n], 0, 0, 0);
                }
            }
        __syncthreads();
    }

    // C/D layout: col = lane&15, row = (lane>>4)*4 + reg   [m89-verified]
#pragma unroll
    for (int m = 0; m < 4; ++m) {
        int row0 = bm + wm * 64 + m * 16 + lg * 4;
#pragma unroll
        for (int n = 0; n < 4; ++n) {
            int col = bn + wn * 64 + n * 16 + lr;
            if (col < N) {
#pragma unroll
                for (int r = 0; r < 4; ++r) {
                    size_t off = (size_t)(row0 + r) * N + col;
                    if (ACCUM) C[off] += acc[m][n][r]; else C[off] = acc[m][n][r];
                }
            }
        }
    }
}

// ---------------- activation quant ----------------
__global__ void k_zero(unsigned* p) { *p = 0u; }

__global__ void k_absmax(const float* __restrict__ zx, unsigned* __restrict__ out) {
    __shared__ float sbuf[256];
    float m = 0.f;
    int total = SEQLEN * CONV_DIM;
    for (int i = blockIdx.x * blockDim.x + threadIdx.x; i < total; i += gridDim.x * blockDim.x) {
        int t = i / CONV_DIM, c = i - t * CONV_DIM;
        float v = fabsf(zx[(long)t * D_IN_PROJ + D_INNER + c]);
        m = fmaxf(m, v);
    }
    sbuf[threadIdx.x] = m; __syncthreads();
    for (int s = 128; s > 0; s >>= 1) {
        if (threadIdx.x < s) sbuf[threadIdx.x] = fmaxf(sbuf[threadIdx.x], sbuf[threadIdx.x + s]);
        __syncthreads();
    }
    if (threadIdx.x == 0) atomicMax(out, __float_as_uint(sbuf[0]));
}

__global__ void k_quant(const float* __restrict__ zx, const unsigned* __restrict__ mx,
                        float* __restrict__ xq) {
    int i = blockIdx.x * blockDim.x + threadIdx.x;
    if (i >= SEQLEN * CONV_DIM) return;
    float s = __uint_as_float(*mx) / (127.0f + 1e-8f);
    int t = i / CONV_DIM, c = i - t * CONV_DIM;
    float v = rintf(zx[(long)t * D_IN_PROJ + D_INNER + c] / s);
    xq[i] = fminf(fmaxf(v, -128.0f), 127.0f);
}

// ---------------- depthwise conv (zp-not-subtracted, like ref) + silu ----------------
__global__ void k_conv(const float* __restrict__ xq, const float* __restrict__ qcw,
                       const float* __restrict__ cb, const float* __restrict__ cscale,
                       const unsigned* __restrict__ mx, float* __restrict__ xact) {
    int i = blockIdx.x * blockDim.x + threadIdx.x;
    if (i >= SEQLEN * CONV_DIM) return;
    float s = __uint_as_float(*mx) / (127.0f + 1e-8f);
    int t = i / CONV_DIM, c = i - t * CONV_DIM;
    float acc = cb[c];
#pragma unroll
    for (int k = 0; k < D_CONV; ++k) {
        int tt = t - (D_CONV - 1) + k;
        if (tt >= 0) acc = fmaf(xq[(long)tt * CONV_DIM + c], qcw[c * D_CONV + k], acc);
    }
    float v = acc * (cscale[0] * s);
    xact[i] = v / (1.0f + expf(-v));
}

// ---------------- SSM scan: grid (head, n-quarter, p-half), partials via atomicAdd ----------------
__global__ __launch_bounds__(256) void k_scan(const float* __restrict__ xact,
                                              const float* __restrict__ zx,
                                              const float* __restrict__ dtbias,
                                              const float* __restrict__ A_log,
                                              float* __restrict__ y) {
    const int head = blockIdx.x;
    const int q = blockIdx.y;    // n quarter: n in [q*32, q*32+32)
    const int ph = blockIdx.z;   // p half:   p in [ph*32, ph*32+32)
    const int tid = threadIdx.x;
    const int w = tid >> 6, l = tid & 63;
    const int nc = l & 7, poff = l >> 3;
    const int pl = w * 8 + poff;          // 0..31 local p
    const int p = ph * 32 + pl;
    const int nloc = nc * 4;              // 0..28 within quarter

    __shared__ float sB[2][8][32], sC[2][8][32], sX[2][8][32];
    __shared__ float sDt[2][8], sA[2][8];

    const float negA = -expf(A_log[head]);
    const float bias = dtbias[head];
    float h0 = 0.f, h1 = 0.f, h2 = 0.f, h3 = 0.f;

    const int stl = tid >> 5;   // staging: timestep-in-chunk 0..7
    const int scc = tid & 31;   // staging: column 0..31

    auto stage = [&](int buf, int t0) {
        size_t rowb = (size_t)(t0 + stl) * CONV_DIM;
        sB[buf][stl][scc] = xact[rowb + D_INNER + q * 32 + scc];
        sC[buf][stl][scc] = xact[rowb + D_INNER + D_STATE + q * 32 + scc];
        sX[buf][stl][scc] = xact[rowb + head * HEADDIM + ph * 32 + scc];
        if (tid < 8) {
            int t = t0 + tid;
            float v = zx[(size_t)t * D_IN_PROJ + (D_INNER + CONV_DIM) + head] + bias;
            float dtv = fmaxf(v, 0.f) + log1pf(expf(-fabsf(v)));
            sDt[buf][tid] = dtv;
            sA[buf][tid] = expf(dtv * negA);
        }
    };

    stage(0, 0);
    __syncthreads();
    for (int ch = 0; ch < SEQLEN / 8; ++ch) {
        int buf = ch & 1;
        if (ch + 1 < SEQLEN / 8) stage(buf ^ 1, (ch + 1) * 8);
#pragma unroll
        for (int tl = 0; tl < 8; ++tl) {
            float dtv = sDt[buf][tl], a = sA[buf][tl];
            float xdt = sX[buf][tl][pl] * dtv;
            float4 Bv = *(const float4*)&sB[buf][tl][nloc];
            float4 Cv = *(const float4*)&sC[buf][tl][nloc];
            h0 = fmaf(a, h0, xdt * Bv.x);
            h1 = fmaf(a, h1, xdt * Bv.y);
            h2 = fmaf(a, h2, xdt * Bv.z);
            h3 = fmaf(a, h3, xdt * Bv.w);
            float accv = fmaf(h0, Cv.x, fmaf(h1, Cv.y, fmaf(h2, Cv.z, h3 * Cv.w)));
            accv += __shfl_xor(accv, 1);
            accv += __shfl_xor(accv, 2);
            accv += __shfl_xor(accv, 4);
            if (nc == 0)
                atomicAdd(&y[(size_t)(ch * 8 + tl) * D_INNER + head * HEADDIM + p], accv);
        }
        __syncthreads();
    }
}

// ---------------- gate: (y + x*D) * silu(z), then rmsnorm(1536) ----------------
__global__ void k_gatenorm(const float* __restrict__ ybuf, const float* __restrict__ zx,
                           const float* __restrict__ xact, const float* __restrict__ dpar,
                           const float* __restrict__ mnw, float* __restrict__ y3) {
    __shared__ float sbuf[256];
    int t = blockIdx.x;
    const float* yr = ybuf + (long)t * D_INNER;
    const float* zr = zx + (long)t * D_IN_PROJ;
    const float* xa = xact + (long)t * CONV_DIM;
    float vals[6];
    float ss = 0.f;
#pragma unroll
    for (int j = 0; j < 6; ++j) {
        int e = threadIdx.x + j * 256;
        float z = zr[e];
        float v = (yr[e] + xa[e] * dpar[e >> 6]) * (z / (1.0f + expf(-z)));
        vals[j] = v; ss += v * v;
    }
    sbuf[threadIdx.x] = ss; __syncthreads();
    for (int s = 128; s > 0; s >>= 1) {
        if (threadIdx.x < s) sbuf[threadIdx.x] += sbuf[threadIdx.x + s];
        __syncthreads();
    }
    float scale = 1.0f / sqrtf(sbuf[0] / (float)D_INNER + EPS);
#pragma unroll
    for (int j = 0; j < 6; ++j) {
        int e = threadIdx.x + j * 256;
        y3[(long)t * D_INNER + e] = vals[j] * scale * mnw[e];
    }
}

extern "C" void kernel_launch(void* const* d_in, const int* in_sizes, int n_in,
                              void* d_out, int out_size, void* d_ws, size_t ws_size,
                              hipStream_t stream) {
    const int*   ids    = (const int*)d_in[0];
    const float* emb    = (const float*)d_in[1];
    const float* norm_w = (const float*)d_in[2];
    const float* inw    = (const float*)d_in[3];
    const float* qconv  = (const float*)d_in[4];
    const float* cscale = (const float*)d_in[5];
    const float* convb  = (const float*)d_in[6];
    const float* dtbias = (const float*)d_in[7];
    const float* alog   = (const float*)d_in[8];
    const float* dpar   = (const float*)d_in[9];
    const float* mnw    = (const float*)d_in[10];
    const float* outw   = (const float*)d_in[11];
    const float* normf  = (const float*)d_in[12];
    const float* lmw    = (const float*)d_in[13];
    float* out = (float*)d_out;

    float* p = (float*)d_ws;
    float* xres = p; p += (long)SEQLEN * D_MODEL;
    float* u    = p; p += (long)SEQLEN * D_MODEL;
    float* zx   = p; p += (long)SEQLEN * D_IN_PROJ;
    float* xq   = p; p += (long)SEQLEN * CONV_DIM;
    float* xact = p; p += (long)SEQLEN * CONV_DIM;
    float* ybuf = p; p += (long)SEQLEN * D_INNER;
    float* y3   = p; p += (long)SEQLEN * D_INNER;
    unsigned* mx = (unsigned*)p;

    k_embed<<<SEQLEN, 256, 0, stream>>>(ids, emb, xres);

    int nq = SEQLEN * CONV_DIM;
    for (int l = 0; l < N_LAYER; ++l) {
        k_lutnorm<<<SEQLEN, 256, 0, stream>>>(xres, norm_w + l * D_MODEL, u);
        dim3 g1(SEQLEN / 128, (D_IN_PROJ + 127) / 128);
        k_gemm_mfma<3, false><<<g1, 256, 0, stream>>>(u, inw + (long)l * D_IN_PROJ * D_MODEL,
                                                      zx, SEQLEN, D_IN_PROJ, D_MODEL);
        k_zero<<<1, 1, 0, stream>>>(mx);
        k_absmax<<<256, 256, 0, stream>>>(zx, mx);
        k_quant<<<(nq + 255) / 256, 256, 0, stream>>>(zx, mx, xq);
        k_conv<<<(nq + 255) / 256, 256, 0, stream>>>(xq, qconv + l * CONV_DIM * D_CONV,
                                                     convb + l * CONV_DIM, cscale + l, mx, xact);
        hipMemsetAsync(ybuf, 0, (size_t)SEQLEN * D_INNER * sizeof(float), stream);
        dim3 gs(NHEADS, 4, 2);
        k_scan<<<gs, 256, 0, stream>>>(xact, zx, dtbias + l * NHEADS, alog + l * NHEADS, ybuf);
        k_gatenorm<<<SEQLEN, 256, 0, stream>>>(ybuf, zx, xact, dpar + l * NHEADS,
                                               mnw + l * D_INNER, y3);
        dim3 g2(SEQLEN / 128, (D_MODEL + 127) / 128);
        k_gemm_mfma<3, true><<<g2, 256, 0, stream>>>(y3, outw + (long)l * D_MODEL * D_INNER,
                                                     xres, SEQLEN, D_MODEL, D_INNER);
    }
    k_lutnorm<<<SEQLEN, 256, 0, stream>>>(xres, normf, u);
    dim3 g3(SEQLEN / 128, (VOCAB + 127) / 128);
    k_gemm_mfma<1, false><<<g3, 256, 0, stream>>>(u, lmw, out, SEQLEN, VOCAB, D_MODEL);
}

// Round 4
// 2542.668 us; speedup vs baseline: 5.1846x; 1.7208x over previous
//
#include <hip/hip_runtime.h>
#include <math.h>

#define D_MODEL 768
#define N_LAYER 8
#define D_STATE 128
#define D_CONV 4
#define HEADDIM 64
#define D_INNER 1536
#define NHEADS 24
#define D_IN_PROJ 3352   // 2*D_INNER + 2*D_STATE + NHEADS
#define CONV_DIM 1792    // D_INNER + 2*D_STATE
#define SEQLEN 1024
#define VOCAB 50288
#define EPS 1e-5f
#define T_SEG 32
#define NSEG  32         // SEQLEN / T_SEG

typedef __bf16 bf16x8 __attribute__((ext_vector_type(8)));
typedef float f32x4 __attribute__((ext_vector_type(4)));

__device__ inline unsigned short f2bf(float x) {
    union { float f; unsigned u; } v; v.f = x;
    unsigned r = v.u + 0x7fffu + ((v.u >> 16) & 1u);
    return (unsigned short)(r >> 16);
}
__device__ inline float bf2f(unsigned short b) {
    union { unsigned u; float f; } v; v.u = ((unsigned)b) << 16;
    return v.f;
}

// ---------------- embedding gather ----------------
__global__ void k_embed(const int* __restrict__ ids, const float* __restrict__ emb,
                        float* __restrict__ x) {
    int t = blockIdx.x;
    int id = ids[t];
    const float* er = emb + (long)id * D_MODEL;
    for (int d = threadIdx.x; d < D_MODEL; d += blockDim.x)
        x[(long)t * D_MODEL + d] = er[d];
}

// ---------------- LUT rmsnorm (768) ----------------
__global__ void k_lutnorm(const float* __restrict__ x, const float* __restrict__ w,
                          float* __restrict__ out) {
    __shared__ float sbuf[256];
    int t = blockIdx.x;
    const float* xr = x + (long)t * D_MODEL;
    float ss = 0.f;
    for (int d = threadIdx.x; d < D_MODEL; d += 256) { float v = xr[d]; ss += v * v; }
    sbuf[threadIdx.x] = ss; __syncthreads();
    for (int s = 128; s > 0; s >>= 1) {
        if (threadIdx.x < s) sbuf[threadIdx.x] += sbuf[threadIdx.x + s];
        __syncthreads();
    }
    float rms = sbuf[0] / (float)D_MODEL + EPS;
    const float X0 = 1e-5f;
    const float STEP = (10.0f - 1e-5f) / 255.0f;
    int idx = (int)ceilf((rms - X0) / STEP);
    idx = min(max(idx, 0), 255);
    while (idx > 0 && (X0 + (float)(idx - 1) * STEP) >= rms) --idx;
    while (idx < 255 && (X0 + (float)idx * STEP) < rms) ++idx;
    float scale = 1.0f / sqrtf(X0 + (float)idx * STEP);
    for (int d = threadIdx.x; d < D_MODEL; d += 256)
        out[(long)t * D_MODEL + d] = xr[d] * scale * w[d];
}

// ---------------- MFMA GEMM: C[M,N] (+)= A[M,K] * B[N,K]^T (fp32 in, bf16x2 split) ----
template <int PASSES, bool ACCUM>
__global__ __launch_bounds__(256) void k_gemm_mfma(const float* __restrict__ A,
                                                   const float* __restrict__ B,
                                                   float* __restrict__ C,
                                                   int M, int N, int K) {
    __shared__ __align__(16) unsigned short Ah[4][128][8];
    __shared__ __align__(16) unsigned short Bh[4][128][8];
    __shared__ __align__(16) unsigned short Al[(PASSES == 3) ? 4 : 1][128][8];
    __shared__ __align__(16) unsigned short Bl[(PASSES == 3) ? 4 : 1][128][8];

    const int bm = blockIdx.x * 128, bn = blockIdx.y * 128;
    const int tid = threadIdx.x;
    const int rr = tid >> 2, g = tid & 3;
    const int w = tid >> 6, l = tid & 63;
    const int wm = w >> 1, wn = w & 1;
    const int lr = l & 15, lg = l >> 4;

    f32x4 acc[4][4];
#pragma unroll
    for (int m = 0; m < 4; ++m)
#pragma unroll
        for (int n = 0; n < 4; ++n) acc[m][n] = (f32x4){0.f, 0.f, 0.f, 0.f};

    for (int k0 = 0; k0 < K; k0 += 32) {
#pragma unroll
        for (int half = 0; half < 2; ++half) {
            int r = rr + half * 64;
            {
                const float* s = A + (size_t)(bm + r) * K + k0 + g * 8;
                float4 f0 = *(const float4*)s;
                float4 f1 = *(const float4*)(s + 4);
                float ff[8] = {f0.x, f0.y, f0.z, f0.w, f1.x, f1.y, f1.z, f1.w};
                unsigned short h[8], lo[8];
#pragma unroll
                for (int i = 0; i < 8; ++i) {
                    h[i] = f2bf(ff[i]);
                    if (PASSES == 3) lo[i] = f2bf(ff[i] - bf2f(h[i]));
                }
                uint4 uh = make_uint4(h[0] | (h[1] << 16), h[2] | (h[3] << 16),
                                      h[4] | (h[5] << 16), h[6] | (h[7] << 16));
                *(uint4*)&Ah[g][r][0] = uh;
                if (PASSES == 3) {
                    uint4 ul = make_uint4(lo[0] | (lo[1] << 16), lo[2] | (lo[3] << 16),
                                          lo[4] | (lo[5] << 16), lo[6] | (lo[7] << 16));
                    *(uint4*)&Al[g][r][0] = ul;
                }
            }
            {
                int rB = bn + r;
                float ff[8] = {0.f, 0.f, 0.f, 0.f, 0.f, 0.f, 0.f, 0.f};
                if (rB < N) {
                    const float* s = B + (size_t)rB * K + k0 + g * 8;
                    float4 f0 = *(const float4*)s;
                    float4 f1 = *(const float4*)(s + 4);
                    ff[0] = f0.x; ff[1] = f0.y; ff[2] = f0.z; ff[3] = f0.w;
                    ff[4] = f1.x; ff[5] = f1.y; ff[6] = f1.z; ff[7] = f1.w;
                }
                unsigned short h[8], lo[8];
#pragma unroll
                for (int i = 0; i < 8; ++i) {
                    h[i] = f2bf(ff[i]);
                    if (PASSES == 3) lo[i] = f2bf(ff[i] - bf2f(h[i]));
                }
                uint4 uh = make_uint4(h[0] | (h[1] << 16), h[2] | (h[3] << 16),
                                      h[4] | (h[5] << 16), h[6] | (h[7] << 16));
                *(uint4*)&Bh[g][r][0] = uh;
                if (PASSES == 3) {
                    uint4 ul = make_uint4(lo[0] | (lo[1] << 16), lo[2] | (lo[3] << 16),
                                          lo[4] | (lo[5] << 16), lo[6] | (lo[7] << 16));
                    *(uint4*)&Bl[g][r][0] = ul;
                }
            }
        }
        __syncthreads();

        bf16x8 ah[4], bh[4], al_[4], bl_[4];
#pragma unroll
        for (int m = 0; m < 4; ++m) {
            int row = wm * 64 + m * 16 + lr;
            ah[m] = *(const bf16x8*)&Ah[lg][row][0];
            if (PASSES == 3) al_[m] = *(const bf16x8*)&Al[lg][row][0];
        }
#pragma unroll
        for (int n = 0; n < 4; ++n) {
            int row = wn * 64 + n * 16 + lr;
            bh[n] = *(const bf16x8*)&Bh[lg][row][0];
            if (PASSES == 3) bl_[n] = *(const bf16x8*)&Bl[lg][row][0];
        }
#pragma unroll
        for (int m = 0; m < 4; ++m)
#pragma unroll
            for (int n = 0; n < 4; ++n) {
                acc[m][n] = __builtin_amdgcn_mfma_f32_16x16x32_bf16(ah[m], bh[n], acc[m][n], 0, 0, 0);
                if (PASSES == 3) {
                    acc[m][n] = __builtin_amdgcn_mfma_f32_16x16x32_bf16(al_[m], bh[n], acc[m][n], 0, 0, 0);
                    acc[m][n] = __builtin_amdgcn_mfma_f32_16x16x32_bf16(ah[m], bl_[n], acc[m][n], 0, 0, 0);
                }
            }
        __syncthreads();
    }

#pragma unroll
    for (int m = 0; m < 4; ++m) {
        int row0 = bm + wm * 64 + m * 16 + lg * 4;
#pragma unroll
        for (int n = 0; n < 4; ++n) {
            int col = bn + wn * 64 + n * 16 + lr;
            if (col < N) {
#pragma unroll
                for (int r = 0; r < 4; ++r) {
                    size_t off = (size_t)(row0 + r) * N + col;
                    if (ACCUM) C[off] += acc[m][n][r]; else C[off] = acc[m][n][r];
                }
            }
        }
    }
}

// ---------------- MFMA GEMM with pre-converted bf16 B ----------------
template <bool ACCUM>
__global__ __launch_bounds__(256) void k_gemm_bfB(const float* __restrict__ A,
                                                  const unsigned short* __restrict__ Bbf,
                                                  float* __restrict__ C,
                                                  int M, int N, int K) {
    __shared__ __align__(16) unsigned short Ah[4][128][8];
    __shared__ __align__(16) unsigned short Bh[4][128][8];

    const int bm = blockIdx.x * 128, bn = blockIdx.y * 128;
    const int tid = threadIdx.x;
    const int rr = tid >> 2, g = tid & 3;
    const int w = tid >> 6, l = tid & 63;
    const int wm = w >> 1, wn = w & 1;
    const int lr = l & 15, lg = l >> 4;

    f32x4 acc[4][4];
#pragma unroll
    for (int m = 0; m < 4; ++m)
#pragma unroll
        for (int n = 0; n < 4; ++n) acc[m][n] = (f32x4){0.f, 0.f, 0.f, 0.f};

    for (int k0 = 0; k0 < K; k0 += 32) {
#pragma unroll
        for (int half = 0; half < 2; ++half) {
            int r = rr + half * 64;
            {
                const float* s = A + (size_t)(bm + r) * K + k0 + g * 8;
                float4 f0 = *(const float4*)s;
                float4 f1 = *(const float4*)(s + 4);
                float ff[8] = {f0.x, f0.y, f0.z, f0.w, f1.x, f1.y, f1.z, f1.w};
                unsigned short h[8];
#pragma unroll
                for (int i = 0; i < 8; ++i) h[i] = f2bf(ff[i]);
                uint4 uh = make_uint4(h[0] | (h[1] << 16), h[2] | (h[3] << 16),
                                      h[4] | (h[5] << 16), h[6] | (h[7] << 16));
                *(uint4*)&Ah[g][r][0] = uh;
            }
            {
                int rB = bn + r;
                uint4 ub = make_uint4(0, 0, 0, 0);
                if (rB < N) ub = *(const uint4*)(Bbf + (size_t)rB * K + k0 + g * 8);
                *(uint4*)&Bh[g][r][0] = ub;
            }
        }
        __syncthreads();

        bf16x8 ah[4], bh[4];
#pragma unroll
        for (int m = 0; m < 4; ++m) ah[m] = *(const bf16x8*)&Ah[lg][wm * 64 + m * 16 + lr][0];
#pragma unroll
        for (int n = 0; n < 4; ++n) bh[n] = *(const bf16x8*)&Bh[lg][wn * 64 + n * 16 + lr][0];
#pragma unroll
        for (int m = 0; m < 4; ++m)
#pragma unroll
            for (int n = 0; n < 4; ++n)
                acc[m][n] = __builtin_amdgcn_mfma_f32_16x16x32_bf16(ah[m], bh[n], acc[m][n], 0, 0, 0);
        __syncthreads();
    }

#pragma unroll
    for (int m = 0; m < 4; ++m) {
        int row0 = bm + wm * 64 + m * 16 + lg * 4;
#pragma unroll
        for (int n = 0; n < 4; ++n) {
            int col = bn + wn * 64 + n * 16 + lr;
            if (col < N) {
#pragma unroll
                for (int r = 0; r < 4; ++r) {
                    size_t off = (size_t)(row0 + r) * N + col;
                    if (ACCUM) C[off] += acc[m][n][r]; else C[off] = acc[m][n][r];
                }
            }
        }
    }
}

// ---------------- fp32 -> bf16 convert (weights) ----------------
__global__ void k_f2bf(const float* __restrict__ src, unsigned short* __restrict__ dst, int n8) {
    int i = blockIdx.x * 256 + threadIdx.x;
    int stride = gridDim.x * 256;
    for (; i < n8; i += stride) {
        const float* s = src + (size_t)i * 8;
        float4 a = *(const float4*)s, b = *(const float4*)(s + 4);
        float ff[8] = {a.x, a.y, a.z, a.w, b.x, b.y, b.z, b.w};
        unsigned short h[8];
#pragma unroll
        for (int j = 0; j < 8; ++j) h[j] = f2bf(ff[j]);
        uint4 u = make_uint4(h[0] | (h[1] << 16), h[2] | (h[3] << 16),
                             h[4] | (h[5] << 16), h[6] | (h[7] << 16));
        *(uint4*)(dst + (size_t)i * 8) = u;
    }
}

// ---------------- activation absmax ----------------
__global__ void k_zero(unsigned* p) { *p = 0u; }

__global__ void k_absmax(const float* __restrict__ zx, unsigned* __restrict__ out) {
    __shared__ float sbuf[256];
    float m = 0.f;
    int total = SEQLEN * CONV_DIM;
    for (int i = blockIdx.x * blockDim.x + threadIdx.x; i < total; i += gridDim.x * blockDim.x) {
        int t = i / CONV_DIM, c = i - t * CONV_DIM;
        float v = fabsf(zx[(long)t * D_IN_PROJ + D_INNER + c]);
        m = fmaxf(m, v);
    }
    sbuf[threadIdx.x] = m; __syncthreads();
    for (int s = 128; s > 0; s >>= 1) {
        if (threadIdx.x < s) sbuf[threadIdx.x] = fmaxf(sbuf[threadIdx.x], sbuf[threadIdx.x + s]);
        __syncthreads();
    }
    if (threadIdx.x == 0) atomicMax(out, __float_as_uint(sbuf[0]));
}

// ---------------- fused quant + depthwise conv + silu ----------------
__global__ void k_convq(const float* __restrict__ zx, const float* __restrict__ qcw,
                        const float* __restrict__ cb, const float* __restrict__ cscale,
                        const unsigned* __restrict__ mx, float* __restrict__ xact) {
    int i = blockIdx.x * blockDim.x + threadIdx.x;
    if (i >= SEQLEN * CONV_DIM) return;
    float s = __uint_as_float(*mx) / (127.0f + 1e-8f);
    float inv_s = 1.0f / s;
    int t = i / CONV_DIM, c = i - t * CONV_DIM;
    float acc = cb[c];
#pragma unroll
    for (int k = 0; k < D_CONV; ++k) {
        int tt = t - (D_CONV - 1) + k;
        if (tt >= 0) {
            float q = rintf(zx[(size_t)tt * D_IN_PROJ + D_INNER + c] * inv_s);
            q = fminf(fmaxf(q, -128.0f), 127.0f);
            acc = fmaf(q, qcw[c * D_CONV + k], acc);
        }
    }
    float v = acc * (cscale[0] * s);
    xact[i] = v / (1.0f + expf(-v));
}

// ================= chunked SSM scan =================
// S1: per-(head,seg) local scan from h=0; writes local y, final state hloc, decay prefix dpre
__global__ __launch_bounds__(256) void k_scan_local(
    const float* __restrict__ xact, const float* __restrict__ zx,
    const float* __restrict__ dtbias, const float* __restrict__ A_log,
    float* __restrict__ y, float* __restrict__ hloc, float* __restrict__ dpre) {
    const int head = blockIdx.x;
    const int seg  = blockIdx.y;
    const int tid  = threadIdx.x;
    const int p  = tid >> 2;          // 0..63
    const int nc = tid & 3;           // n group of 32
    const int t0 = seg * T_SEG;

    __shared__ float4 sB4[T_SEG][32];
    __shared__ float4 sC4[T_SEG][32];
    __shared__ float  sX[T_SEG][64];
    __shared__ float  sDt[T_SEG], sA[T_SEG];

    // stage B,C swizzled at float4 granularity (self-cancelling slot rotation)
#pragma unroll
    for (int it = 0; it < 4; ++it) {
        int slot = tid + it * 256;        // 1024 slots = 32 t x 32 c4
        int t = slot >> 5, c4 = slot & 31;
        const float* rowp = xact + (size_t)(t0 + t) * CONV_DIM + D_INNER;
        float4 bv = *(const float4*)(rowp + c4 * 4);
        float4 cv = *(const float4*)(rowp + D_STATE + c4 * 4);
        int grp = c4 >> 3, r4 = c4 & 7;
        int sl = grp * 8 + ((r4 + 2 * grp) & 7);
        sB4[t][sl] = bv;
        sC4[t][sl] = cv;
    }
#pragma unroll
    for (int it = 0; it < 2; ++it) {
        int slot = tid + it * 256;        // 512 slots = 32 t x 16 c4
        int t = slot >> 4, c4 = slot & 15;
        *(float4*)&sX[t][c4 * 4] =
            *(const float4*)(xact + (size_t)(t0 + t) * CONV_DIM + head * HEADDIM + c4 * 4);
    }
    if (tid < T_SEG) {
        float v = zx[(size_t)(t0 + tid) * D_IN_PROJ + (D_INNER + CONV_DIM) + head] + dtbias[head];
        float dtv = fmaxf(v, 0.f) + log1pf(expf(-fabsf(v)));
        sDt[tid] = dtv;
        sA[tid] = expf(dtv * (-expf(A_log[head])));
    }
    __syncthreads();

    float h[32];
#pragma unroll
    for (int j = 0; j < 32; ++j) h[j] = 0.f;
    float d = 1.f;
    float* yrow = y + head * HEADDIM + p;

    for (int t = 0; t < T_SEG; ++t) {
        float a = sA[t], dtv = sDt[t];
        float xdt = sX[t][p] * dtv;
        d *= a;
        float acc = 0.f;
#pragma unroll
        for (int j4 = 0; j4 < 8; ++j4) {
            int sl = nc * 8 + ((j4 + 2 * nc) & 7);
            float4 Bv = sB4[t][sl];
            float4 Cv = sC4[t][sl];
            h[j4 * 4 + 0] = fmaf(a, h[j4 * 4 + 0], xdt * Bv.x); acc = fmaf(h[j4 * 4 + 0], Cv.x, acc);
            h[j4 * 4 + 1] = fmaf(a, h[j4 * 4 + 1], xdt * Bv.y); acc = fmaf(h[j4 * 4 + 1], Cv.y, acc);
            h[j4 * 4 + 2] = fmaf(a, h[j4 * 4 + 2], xdt * Bv.z); acc = fmaf(h[j4 * 4 + 2], Cv.z, acc);
            h[j4 * 4 + 3] = fmaf(a, h[j4 * 4 + 3], xdt * Bv.w); acc = fmaf(h[j4 * 4 + 3], Cv.w, acc);
        }
        acc += __shfl_xor(acc, 1);
        acc += __shfl_xor(acc, 2);
        if (nc == 0) yrow[(size_t)(t0 + t) * D_INNER] = acc;
        if (tid == 0) dpre[(head * NSEG + seg) * T_SEG + t] = d;
    }

    float* hb = hloc + ((size_t)(head * NSEG + seg) * 64 + p) * 128 + nc * 32;
#pragma unroll
    for (int j4 = 0; j4 < 8; ++j4)
        *(float4*)(hb + j4 * 4) =
            make_float4(h[j4 * 4], h[j4 * 4 + 1], h[j4 * 4 + 2], h[j4 * 4 + 3]);
}

// S2: segment-level scan over states: H[seg] = hloc[seg] + P_seg * H[seg-1] (in place)
__global__ __launch_bounds__(256) void k_scan_seg(float* __restrict__ hloc,
                                                  const float* __restrict__ dpre) {
    int g = blockIdx.x * 256 + threadIdx.x;   // 49152 = 24 heads * 2048 float4
    int head = g >> 11;
    int e4 = g & 2047;
    float4 run = make_float4(0.f, 0.f, 0.f, 0.f);
    for (int seg = 0; seg < NSEG; ++seg) {
        float d = dpre[(head * NSEG + seg) * T_SEG + (T_SEG - 1)];
        float4* ptr = (float4*)hloc + (size_t)(head * NSEG + seg) * 2048 + e4;
        float4 v = *ptr;
        run.x = fmaf(d, run.x, v.x);
        run.y = fmaf(d, run.y, v.y);
        run.z = fmaf(d, run.z, v.z);
        run.w = fmaf(d, run.w, v.w);
        *ptr = run;
    }
}

// S3: boundary correction y_t += d_t * (C_t . H_prev)
__global__ __launch_bounds__(256) void k_scan_fix(
    const float* __restrict__ xact, const float* __restrict__ hloc,
    const float* __restrict__ dpre, float* __restrict__ y) {
    const int head = blockIdx.x;
    const int seg  = blockIdx.y + 1;
    const int tid  = threadIdx.x;
    const int p  = tid >> 2;
    const int nc = tid & 3;
    const int t0 = seg * T_SEG;

    __shared__ float4 sC4[T_SEG][32];
    __shared__ float  sD[T_SEG];

#pragma unroll
    for (int it = 0; it < 4; ++it) {
        int slot = tid + it * 256;
        int t = slot >> 5, c4 = slot & 31;
        float4 cv = *(const float4*)(xact + (size_t)(t0 + t) * CONV_DIM + D_INNER + D_STATE + c4 * 4);
        int grp = c4 >> 3, r4 = c4 & 7;
        sC4[t][grp * 8 + ((r4 + 2 * grp) & 7)] = cv;
    }
    if (tid < T_SEG) sD[tid] = dpre[(head * NSEG + seg) * T_SEG + tid];
    __syncthreads();

    float H[32];
    const float* hb = hloc + ((size_t)(head * NSEG + seg - 1) * 64 + p) * 128 + nc * 32;
#pragma unroll
    for (int j4 = 0; j4 < 8; ++j4) {
        float4 v = *(const float4*)(hb + j4 * 4);
        H[j4 * 4 + 0] = v.x; H[j4 * 4 + 1] = v.y; H[j4 * 4 + 2] = v.z; H[j4 * 4 + 3] = v.w;
    }
    float* yrow = y + head * HEADDIM + p;
    for (int t = 0; t < T_SEG; ++t) {
        float acc = 0.f;
#pragma unroll
        for (int j4 = 0; j4 < 8; ++j4) {
            int sl = nc * 8 + ((j4 + 2 * nc) & 7);
            float4 Cv = sC4[t][sl];
            acc = fmaf(H[j4 * 4 + 0], Cv.x, acc);
            acc = fmaf(H[j4 * 4 + 1], Cv.y, acc);
            acc = fmaf(H[j4 * 4 + 2], Cv.z, acc);
            acc = fmaf(H[j4 * 4 + 3], Cv.w, acc);
        }
        acc += __shfl_xor(acc, 1);
        acc += __shfl_xor(acc, 2);
        if (nc == 0) yrow[(size_t)(t0 + t) * D_INNER] += sD[t] * acc;
    }
}

// ---------------- gate: (y + x*D) * silu(z), then rmsnorm(1536) ----------------
__global__ void k_gatenorm(const float* __restrict__ ybuf, const float* __restrict__ zx,
                           const float* __restrict__ xact, const float* __restrict__ dpar,
                           const float* __restrict__ mnw, float* __restrict__ y3) {
    __shared__ float sbuf[256];
    int t = blockIdx.x;
    const float* yr = ybuf + (long)t * D_INNER;
    const float* zr = zx + (long)t * D_IN_PROJ;
    const float* xa = xact + (long)t * CONV_DIM;
    float vals[6];
    float ss = 0.f;
#pragma unroll
    for (int j = 0; j < 6; ++j) {
        int e = threadIdx.x + j * 256;
        float z = zr[e];
        float v = (yr[e] + xa[e] * dpar[e >> 6]) * (z / (1.0f + expf(-z)));
        vals[j] = v; ss += v * v;
    }
    sbuf[threadIdx.x] = ss; __syncthreads();
    for (int s = 128; s > 0; s >>= 1) {
        if (threadIdx.x < s) sbuf[threadIdx.x] += sbuf[threadIdx.x + s];
        __syncthreads();
    }
    float scale = 1.0f / sqrtf(sbuf[0] / (float)D_INNER + EPS);
#pragma unroll
    for (int j = 0; j < 6; ++j) {
        int e = threadIdx.x + j * 256;
        y3[(long)t * D_INNER + e] = vals[j] * scale * mnw[e];
    }
}

extern "C" void kernel_launch(void* const* d_in, const int* in_sizes, int n_in,
                              void* d_out, int out_size, void* d_ws, size_t ws_size,
                              hipStream_t stream) {
    const int*   ids    = (const int*)d_in[0];
    const float* emb    = (const float*)d_in[1];
    const float* norm_w = (const float*)d_in[2];
    const float* inw    = (const float*)d_in[3];
    const float* qconv  = (const float*)d_in[4];
    const float* cscale = (const float*)d_in[5];
    const float* convb  = (const float*)d_in[6];
    const float* dtbias = (const float*)d_in[7];
    const float* alog   = (const float*)d_in[8];
    const float* dpar   = (const float*)d_in[9];
    const float* mnw    = (const float*)d_in[10];
    const float* outw   = (const float*)d_in[11];
    const float* normf  = (const float*)d_in[12];
    const float* lmw    = (const float*)d_in[13];
    float* out = (float*)d_out;

    float* p = (float*)d_ws;
    float* xres = p; p += (size_t)SEQLEN * D_MODEL;
    float* u    = p; p += (size_t)SEQLEN * D_MODEL;
    float* zx   = p; p += (size_t)SEQLEN * D_IN_PROJ;
    float* xact = p; p += (size_t)SEQLEN * CONV_DIM;
    float* ybuf = p; p += (size_t)SEQLEN * D_INNER;
    float* y3   = p; p += (size_t)SEQLEN * D_INNER;
    float* hloc = p; p += (size_t)NHEADS * NSEG * HEADDIM * D_STATE;   // 6.3M floats
    float* dpre = p; p += (size_t)NHEADS * NSEG * T_SEG;
    unsigned* mx = (unsigned*)p; p += 16;
    unsigned short* lmwbf = (unsigned short*)p;   // 38.6M bf16

    k_embed<<<SEQLEN, 256, 0, stream>>>(ids, emb, xres);
    k_f2bf<<<4096, 256, 0, stream>>>(lmw, lmwbf, (VOCAB * D_MODEL) / 8);

    int nq = SEQLEN * CONV_DIM;
    for (int l = 0; l < N_LAYER; ++l) {
        k_lutnorm<<<SEQLEN, 256, 0, stream>>>(xres, norm_w + l * D_MODEL, u);
        dim3 g1(SEQLEN / 128, (D_IN_PROJ + 127) / 128);
        k_gemm_mfma<3, false><<<g1, 256, 0, stream>>>(u, inw + (size_t)l * D_IN_PROJ * D_MODEL,
                                                      zx, SEQLEN, D_IN_PROJ, D_MODEL);
        k_zero<<<1, 1, 0, stream>>>(mx);
        k_absmax<<<256, 256, 0, stream>>>(zx, mx);
        k_convq<<<(nq + 255) / 256, 256, 0, stream>>>(zx, qconv + l * CONV_DIM * D_CONV,
                                                      convb + l * CONV_DIM, cscale + l, mx, xact);
        dim3 gs1(NHEADS, NSEG);
        k_scan_local<<<gs1, 256, 0, stream>>>(xact, zx, dtbias + l * NHEADS, alog + l * NHEADS,
                                              ybuf, hloc, dpre);
        k_scan_seg<<<192, 256, 0, stream>>>(hloc, dpre);
        dim3 gs3(NHEADS, NSEG - 1);
        k_scan_fix<<<gs3, 256, 0, stream>>>(xact, hloc, dpre, ybuf);
        k_gatenorm<<<SEQLEN, 256, 0, stream>>>(ybuf, zx, xact, dpar + l * NHEADS,
                                               mnw + l * D_INNER, y3);
        dim3 g2(SEQLEN / 128, (D_MODEL + 127) / 128);
        k_gemm_mfma<3, true><<<g2, 256, 0, stream>>>(y3, outw + (size_t)l * D_MODEL * D_INNER,
                                                     xres, SEQLEN, D_MODEL, D_INNER);
    }
    k_lutnorm<<<SEQLEN, 256, 0, stream>>>(xres, normf, u);
    dim3 g3(SEQLEN / 128, (VOCAB + 127) / 128);
    k_gemm_bfB<false><<<g3, 256, 0, stream>>>(u, lmwbf, out, SEQLEN, VOCAB, D_MODEL);
}

// Round 5
// 1626.900 us; speedup vs baseline: 8.1030x; 1.5629x over previous
//
#include <hip/hip_runtime.h>
#include <math.h>

#define D_MODEL 768
#define N_LAYER 8
#define D_STATE 128
#define D_CONV 4
#define HEADDIM 64
#define D_INNER 1536
#define NHEADS 24
#define D_IN_PROJ 3352   // 2*D_INNER + 2*D_STATE + NHEADS
#define CONV_DIM 1792    // D_INNER + 2*D_STATE
#define SEQLEN 1024
#define VOCAB 50288
#define EPS 1e-5f
#define T_SEG 32
#define NSEG  32         // SEQLEN / T_SEG

typedef __bf16 bf16x8 __attribute__((ext_vector_type(8)));
typedef float f32x4 __attribute__((ext_vector_type(4)));

__device__ inline unsigned short f2bf(float x) {
    union { float f; unsigned u; } v; v.f = x;
    unsigned r = v.u + 0x7fffu + ((v.u >> 16) & 1u);
    return (unsigned short)(r >> 16);
}
__device__ inline float bf2f(unsigned short b) {
    union { unsigned u; float f; } v; v.u = ((unsigned)b) << 16;
    return v.f;
}

// ---------------- embedding gather ----------------
__global__ void k_embed(const int* __restrict__ ids, const float* __restrict__ emb,
                        float* __restrict__ x) {
    int t = blockIdx.x;
    int id = ids[t];
    const float* er = emb + (long)id * D_MODEL;
    for (int d = threadIdx.x; d < D_MODEL; d += blockDim.x)
        x[(long)t * D_MODEL + d] = er[d];
}

// ---------------- LUT rmsnorm (768) -> fp32 + bf16 hi/lo ----------------
__global__ void k_lutnorm(const float* __restrict__ x, const float* __restrict__ w,
                          float* __restrict__ out, unsigned short* __restrict__ oh,
                          unsigned short* __restrict__ ol) {
    __shared__ float sbuf[256];
    int t = blockIdx.x;
    const float* xr = x + (long)t * D_MODEL;
    float ss = 0.f;
    for (int d = threadIdx.x; d < D_MODEL; d += 256) { float v = xr[d]; ss += v * v; }
    sbuf[threadIdx.x] = ss; __syncthreads();
    for (int s = 128; s > 0; s >>= 1) {
        if (threadIdx.x < s) sbuf[threadIdx.x] += sbuf[threadIdx.x + s];
        __syncthreads();
    }
    float rms = sbuf[0] / (float)D_MODEL + EPS;
    const float X0 = 1e-5f;
    const float STEP = (10.0f - 1e-5f) / 255.0f;
    int idx = (int)ceilf((rms - X0) / STEP);
    idx = min(max(idx, 0), 255);
    while (idx > 0 && (X0 + (float)(idx - 1) * STEP) >= rms) --idx;
    while (idx < 255 && (X0 + (float)idx * STEP) < rms) ++idx;
    float scale = 1.0f / sqrtf(X0 + (float)idx * STEP);
    for (int d = threadIdx.x; d < D_MODEL; d += 256) {
        float v = xr[d] * scale * w[d];
        out[(long)t * D_MODEL + d] = v;
        unsigned short h = f2bf(v);
        oh[(long)t * D_MODEL + d] = h;
        ol[(long)t * D_MODEL + d] = f2bf(v - bf2f(h));
    }
}

// ---------------- fp32 -> bf16 (hi only) ----------------
__global__ void k_f2bf(const float* __restrict__ src, unsigned short* __restrict__ dst, int n8) {
    int i = blockIdx.x * 256 + threadIdx.x;
    int stride = gridDim.x * 256;
    for (; i < n8; i += stride) {
        const float* s = src + (size_t)i * 8;
        float4 a = *(const float4*)s, b = *(const float4*)(s + 4);
        float ff[8] = {a.x, a.y, a.z, a.w, b.x, b.y, b.z, b.w};
        unsigned short h[8];
#pragma unroll
        for (int j = 0; j < 8; ++j) h[j] = f2bf(ff[j]);
        uint4 u = make_uint4(h[0] | (h[1] << 16), h[2] | (h[3] << 16),
                             h[4] | (h[5] << 16), h[6] | (h[7] << 16));
        *(uint4*)(dst + (size_t)i * 8) = u;
    }
}

// ---------------- fp32 -> bf16 hi + lo ----------------
__global__ void k_f2bf2(const float* __restrict__ src, unsigned short* __restrict__ dh,
                        unsigned short* __restrict__ dl, int n8) {
    int i = blockIdx.x * 256 + threadIdx.x;
    int stride = gridDim.x * 256;
    for (; i < n8; i += stride) {
        const float* s = src + (size_t)i * 8;
        float4 a = *(const float4*)s, b = *(const float4*)(s + 4);
        float ff[8] = {a.x, a.y, a.z, a.w, b.x, b.y, b.z, b.w};
        unsigned short h[8], lo[8];
#pragma unroll
        for (int j = 0; j < 8; ++j) {
            h[j] = f2bf(ff[j]);
            lo[j] = f2bf(ff[j] - bf2f(h[j]));
        }
        uint4 uh = make_uint4(h[0] | (h[1] << 16), h[2] | (h[3] << 16),
                              h[4] | (h[5] << 16), h[6] | (h[7] << 16));
        uint4 ul = make_uint4(lo[0] | (lo[1] << 16), lo[2] | (lo[3] << 16),
                              lo[4] | (lo[5] << 16), lo[6] | (lo[7] << 16));
        *(uint4*)(dh + (size_t)i * 8) = uh;
        *(uint4*)(dl + (size_t)i * 8) = ul;
    }
}

// ======= MFMA GEMM, pre-converted bf16 operands, 128x128 tile, 512 thr, XCD swizzle =======
// C[M,N] = A[M,K]*B[N,K]^T, M=1024. PASSES=3: + Al*Bh + Ah*Bl. AMAX: absmax of C cols [1536,3328)
template <int PASSES, bool AMAX>
__global__ __launch_bounds__(512) void k_gemm_big(
    const unsigned short* __restrict__ Agh, const unsigned short* __restrict__ Agl,
    const unsigned short* __restrict__ Bgh, const unsigned short* __restrict__ Bgl,
    float* __restrict__ C, int N, int NT, int K, unsigned* __restrict__ mx) {
    // swizzle: all 8 M-tiles of a column share i%8 -> same XCD (L2 B-reuse)
    const int i = blockIdx.x;
    const int rxcd = i & 7, xm = (i >> 3) & 7, q = i >> 6;
    const int y = q * 8 + rxcd;
    if (y >= NT) return;
    const int bm = xm * 128, bn = y * 128;

    __shared__ __align__(16) unsigned short Ah[4][128][8];
    __shared__ __align__(16) unsigned short Bh[4][128][8];
    __shared__ __align__(16) unsigned short Al[(PASSES == 3) ? 4 : 1][128][8];
    __shared__ __align__(16) unsigned short Bl[(PASSES == 3) ? 4 : 1][128][8];

    const int tid = threadIdx.x;
    const int r = tid >> 2, g = tid & 3;       // staging: row 0..127, k-granule
    const int rsw = r ^ (g << 1);              // write-conflict XOR
    const int w = tid >> 6, l = tid & 63;
    const int wm = w >> 2, wn = w & 3;         // 2x4 waves: 64x32 out each
    const int lr = l & 15, lg = l >> 4;

    f32x4 acc[4][2];
#pragma unroll
    for (int m = 0; m < 4; ++m)
#pragma unroll
        for (int n = 0; n < 2; ++n) acc[m][n] = (f32x4){0.f, 0.f, 0.f, 0.f};

    for (int k0 = 0; k0 < K; k0 += 32) {
        {
            *(uint4*)&Ah[g][rsw][0] = *(const uint4*)(Agh + (size_t)(bm + r) * K + k0 + g * 8);
            if constexpr (PASSES == 3)
                *(uint4*)&Al[g][rsw][0] = *(const uint4*)(Agl + (size_t)(bm + r) * K + k0 + g * 8);
            int rB = bn + r;
            uint4 zb = make_uint4(0, 0, 0, 0);
            uint4 ubh = (rB < N) ? *(const uint4*)(Bgh + (size_t)rB * K + k0 + g * 8) : zb;
            *(uint4*)&Bh[g][rsw][0] = ubh;
            if constexpr (PASSES == 3) {
                uint4 ubl = (rB < N) ? *(const uint4*)(Bgl + (size_t)rB * K + k0 + g * 8) : zb;
                *(uint4*)&Bl[g][rsw][0] = ubl;
            }
        }
        __syncthreads();

        bf16x8 ah[4], al_[4], bh[2], bl_[2];
#pragma unroll
        for (int m = 0; m < 4; ++m) {
            int row = (wm * 64 + m * 16 + lr) ^ (lg << 1);
            ah[m] = *(const bf16x8*)&Ah[lg][row][0];
            if constexpr (PASSES == 3) al_[m] = *(const bf16x8*)&Al[lg][row][0];
        }
#pragma unroll
        for (int n = 0; n < 2; ++n) {
            int row = (wn * 32 + n * 16 + lr) ^ (lg << 1);
            bh[n] = *(const bf16x8*)&Bh[lg][row][0];
            if constexpr (PASSES == 3) bl_[n] = *(const bf16x8*)&Bl[lg][row][0];
        }
#pragma unroll
        for (int m = 0; m < 4; ++m)
#pragma unroll
            for (int n = 0; n < 2; ++n) {
                acc[m][n] = __builtin_amdgcn_mfma_f32_16x16x32_bf16(ah[m], bh[n], acc[m][n], 0, 0, 0);
                if constexpr (PASSES == 3) {
                    acc[m][n] = __builtin_amdgcn_mfma_f32_16x16x32_bf16(al_[m], bh[n], acc[m][n], 0, 0, 0);
                    acc[m][n] = __builtin_amdgcn_mfma_f32_16x16x32_bf16(ah[m], bl_[n], acc[m][n], 0, 0, 0);
                }
            }
        __syncthreads();
    }

    float lmax = 0.f;
#pragma unroll
    for (int m = 0; m < 4; ++m) {
        int row0 = bm + wm * 64 + m * 16 + lg * 4;
#pragma unroll
        for (int n = 0; n < 2; ++n) {
            int col = bn + wn * 32 + n * 16 + lr;
            if (col < N) {
#pragma unroll
                for (int r4 = 0; r4 < 4; ++r4)
                    C[(size_t)(row0 + r4) * N + col] = acc[m][n][r4];
                if (AMAX && col >= D_INNER && col < D_INNER + CONV_DIM) {
#pragma unroll
                    for (int r4 = 0; r4 < 4; ++r4)
                        lmax = fmaxf(lmax, fabsf(acc[m][n][r4]));
                }
            }
        }
    }
    if (AMAX) {
#pragma unroll
        for (int s = 1; s <= 32; s <<= 1) lmax = fmaxf(lmax, __shfl_xor(lmax, s));
        if (l == 0) atomicMax(mx, __float_as_uint(lmax));
    }
}

// ======= out_proj GEMM: 64x64 tile, 256 thr, PASSES=3, C += (residual), XCD swizzle =======
__global__ __launch_bounds__(256) void k_gemm_out(
    const unsigned short* __restrict__ Agh, const unsigned short* __restrict__ Agl,
    const unsigned short* __restrict__ Bgh, const unsigned short* __restrict__ Bgl,
    float* __restrict__ C) {   // M=1024, N=768, K=1536
    const int K = 1536, N = 768;
    const int i = blockIdx.x;
    const int rxcd = i & 7, xm = (i >> 3) & 15, q = i >> 7;
    const int y = q * 8 + rxcd;
    if (y >= 12) return;
    const int bm = xm * 64, bn = y * 64;

    __shared__ __align__(16) unsigned short Ah[4][64][8];
    __shared__ __align__(16) unsigned short Bh[4][64][8];
    __shared__ __align__(16) unsigned short Al[4][64][8];
    __shared__ __align__(16) unsigned short Bl[4][64][8];

    const int tid = threadIdx.x;
    const int r = tid >> 2, g = tid & 3;
    const int rsw = r ^ (g << 1);
    const int w = tid >> 6, l = tid & 63;
    const int wm = w >> 1, wn = w & 1;        // 2x2 waves: 32x32 out each
    const int lr = l & 15, lg = l >> 4;

    f32x4 acc[2][2];
#pragma unroll
    for (int m = 0; m < 2; ++m)
#pragma unroll
        for (int n = 0; n < 2; ++n) acc[m][n] = (f32x4){0.f, 0.f, 0.f, 0.f};

    for (int k0 = 0; k0 < K; k0 += 32) {
        *(uint4*)&Ah[g][rsw][0] = *(const uint4*)(Agh + (size_t)(bm + r) * K + k0 + g * 8);
        *(uint4*)&Al[g][rsw][0] = *(const uint4*)(Agl + (size_t)(bm + r) * K + k0 + g * 8);
        *(uint4*)&Bh[g][rsw][0] = *(const uint4*)(Bgh + (size_t)(bn + r) * K + k0 + g * 8);
        *(uint4*)&Bl[g][rsw][0] = *(const uint4*)(Bgl + (size_t)(bn + r) * K + k0 + g * 8);
        __syncthreads();

        bf16x8 ah[2], al_[2], bh[2], bl_[2];
#pragma unroll
        for (int m = 0; m < 2; ++m) {
            int row = (wm * 32 + m * 16 + lr) ^ (lg << 1);
            ah[m] = *(const bf16x8*)&Ah[lg][row][0];
            al_[m] = *(const bf16x8*)&Al[lg][row][0];
        }
#pragma unroll
        for (int n = 0; n < 2; ++n) {
            int row = (wn * 32 + n * 16 + lr) ^ (lg << 1);
            bh[n] = *(const bf16x8*)&Bh[lg][row][0];
            bl_[n] = *(const bf16x8*)&Bl[lg][row][0];
        }
#pragma unroll
        for (int m = 0; m < 2; ++m)
#pragma unroll
            for (int n = 0; n < 2; ++n) {
                acc[m][n] = __builtin_amdgcn_mfma_f32_16x16x32_bf16(ah[m], bh[n], acc[m][n], 0, 0, 0);
                acc[m][n] = __builtin_amdgcn_mfma_f32_16x16x32_bf16(al_[m], bh[n], acc[m][n], 0, 0, 0);
                acc[m][n] = __builtin_amdgcn_mfma_f32_16x16x32_bf16(ah[m], bl_[n], acc[m][n], 0, 0, 0);
            }
        __syncthreads();
    }

#pragma unroll
    for (int m = 0; m < 2; ++m) {
        int row0 = bm + wm * 32 + m * 16 + lg * 4;
#pragma unroll
        for (int n = 0; n < 2; ++n) {
            int col = bn + wn * 32 + n * 16 + lr;
#pragma unroll
            for (int r4 = 0; r4 < 4; ++r4)
                C[(size_t)(row0 + r4) * N + col] += acc[m][n][r4];
        }
    }
}

// ---------------- fallback fp32-B GEMM (R4 path, used only if ws too small) ----------------
template <int PASSES, bool ACCUM>
__global__ __launch_bounds__(256) void k_gemm_mfma(const float* __restrict__ A,
                                                   const float* __restrict__ B,
                                                   float* __restrict__ C,
                                                   int M, int N, int K) {
    __shared__ __align__(16) unsigned short Ah[4][128][8];
    __shared__ __align__(16) unsigned short Bh[4][128][8];
    __shared__ __align__(16) unsigned short Al[(PASSES == 3) ? 4 : 1][128][8];
    __shared__ __align__(16) unsigned short Bl[(PASSES == 3) ? 4 : 1][128][8];
    const int bm = blockIdx.x * 128, bn = blockIdx.y * 128;
    const int tid = threadIdx.x;
    const int rr = tid >> 2, g = tid & 3;
    const int w = tid >> 6, l = tid & 63;
    const int wm = w >> 1, wn = w & 1;
    const int lr = l & 15, lg = l >> 4;
    f32x4 acc[4][4];
#pragma unroll
    for (int m = 0; m < 4; ++m)
#pragma unroll
        for (int n = 0; n < 4; ++n) acc[m][n] = (f32x4){0.f, 0.f, 0.f, 0.f};
    for (int k0 = 0; k0 < K; k0 += 32) {
#pragma unroll
        for (int half = 0; half < 2; ++half) {
            int r = rr + half * 64;
            {
                const float* s = A + (size_t)(bm + r) * K + k0 + g * 8;
                float4 f0 = *(const float4*)s;
                float4 f1 = *(const float4*)(s + 4);
                float ff[8] = {f0.x, f0.y, f0.z, f0.w, f1.x, f1.y, f1.z, f1.w};
                unsigned short h[8], lo[8];
#pragma unroll
                for (int ii = 0; ii < 8; ++ii) {
                    h[ii] = f2bf(ff[ii]);
                    if (PASSES == 3) lo[ii] = f2bf(ff[ii] - bf2f(h[ii]));
                }
                *(uint4*)&Ah[g][r][0] = make_uint4(h[0] | (h[1] << 16), h[2] | (h[3] << 16),
                                                   h[4] | (h[5] << 16), h[6] | (h[7] << 16));
                if (PASSES == 3)
                    *(uint4*)&Al[g][r][0] = make_uint4(lo[0] | (lo[1] << 16), lo[2] | (lo[3] << 16),
                                                       lo[4] | (lo[5] << 16), lo[6] | (lo[7] << 16));
            }
            {
                int rB = bn + r;
                float ff[8] = {0.f, 0.f, 0.f, 0.f, 0.f, 0.f, 0.f, 0.f};
                if (rB < N) {
                    const float* s = B + (size_t)rB * K + k0 + g * 8;
                    float4 f0 = *(const float4*)s;
                    float4 f1 = *(const float4*)(s + 4);
                    ff[0] = f0.x; ff[1] = f0.y; ff[2] = f0.z; ff[3] = f0.w;
                    ff[4] = f1.x; ff[5] = f1.y; ff[6] = f1.z; ff[7] = f1.w;
                }
                unsigned short h[8], lo[8];
#pragma unroll
                for (int ii = 0; ii < 8; ++ii) {
                    h[ii] = f2bf(ff[ii]);
                    if (PASSES == 3) lo[ii] = f2bf(ff[ii] - bf2f(h[ii]));
                }
                *(uint4*)&Bh[g][r][0] = make_uint4(h[0] | (h[1] << 16), h[2] | (h[3] << 16),
                                                   h[4] | (h[5] << 16), h[6] | (h[7] << 16));
                if (PASSES == 3)
                    *(uint4*)&Bl[g][r][0] = make_uint4(lo[0] | (lo[1] << 16), lo[2] | (lo[3] << 16),
                                                       lo[4] | (lo[5] << 16), lo[6] | (lo[7] << 16));
            }
        }
        __syncthreads();
        bf16x8 ah[4], bh[4], al_[4], bl_[4];
#pragma unroll
        for (int m = 0; m < 4; ++m) {
            int row = wm * 64 + m * 16 + lr;
            ah[m] = *(const bf16x8*)&Ah[lg][row][0];
            if (PASSES == 3) al_[m] = *(const bf16x8*)&Al[lg][row][0];
        }
#pragma unroll
        for (int n = 0; n < 4; ++n) {
            int row = wn * 64 + n * 16 + lr;
            bh[n] = *(const bf16x8*)&Bh[lg][row][0];
            if (PASSES == 3) bl_[n] = *(const bf16x8*)&Bl[lg][row][0];
        }
#pragma unroll
        for (int m = 0; m < 4; ++m)
#pragma unroll
            for (int n = 0; n < 4; ++n) {
                acc[m][n] = __builtin_amdgcn_mfma_f32_16x16x32_bf16(ah[m], bh[n], acc[m][n], 0, 0, 0);
                if (PASSES == 3) {
                    acc[m][n] = __builtin_amdgcn_mfma_f32_16x16x32_bf16(al_[m], bh[n], acc[m][n], 0, 0, 0);
                    acc[m][n] = __builtin_amdgcn_mfma_f32_16x16x32_bf16(ah[m], bl_[n], acc[m][n], 0, 0, 0);
                }
            }
        __syncthreads();
    }
#pragma unroll
    for (int m = 0; m < 4; ++m) {
        int row0 = bm + wm * 64 + m * 16 + lg * 4;
#pragma unroll
        for (int n = 0; n < 4; ++n) {
            int col = bn + wn * 64 + n * 16 + lr;
            if (col < N) {
#pragma unroll
                for (int r4 = 0; r4 < 4; ++r4) {
                    size_t off = (size_t)(row0 + r4) * N + col;
                    if (ACCUM) C[off] += acc[m][n][r4]; else C[off] = acc[m][n][r4];
                }
            }
        }
    }
}

// ---------------- standalone absmax (fallback path only) ----------------
__global__ void k_absmax(const float* __restrict__ zx, unsigned* __restrict__ out) {
    __shared__ float sbuf[256];
    float m = 0.f;
    int total = SEQLEN * CONV_DIM;
    for (int i = blockIdx.x * blockDim.x + threadIdx.x; i < total; i += gridDim.x * blockDim.x) {
        int t = i / CONV_DIM, c = i - t * CONV_DIM;
        float v = fabsf(zx[(long)t * D_IN_PROJ + D_INNER + c]);
        m = fmaxf(m, v);
    }
    sbuf[threadIdx.x] = m; __syncthreads();
    for (int s = 128; s > 0; s >>= 1) {
        if (threadIdx.x < s) sbuf[threadIdx.x] = fmaxf(sbuf[threadIdx.x], sbuf[threadIdx.x + s]);
        __syncthreads();
    }
    if (threadIdx.x == 0) atomicMax(out, __float_as_uint(sbuf[0]));
}

// ---------------- fused quant + depthwise conv + silu ----------------
__global__ void k_convq(const float* __restrict__ zx, const float* __restrict__ qcw,
                        const float* __restrict__ cb, const float* __restrict__ cscale,
                        const unsigned* __restrict__ mx, float* __restrict__ xact) {
    int i = blockIdx.x * blockDim.x + threadIdx.x;
    if (i >= SEQLEN * CONV_DIM) return;
    float s = __uint_as_float(*mx) / (127.0f + 1e-8f);
    float inv_s = 1.0f / s;
    int t = i / CONV_DIM, c = i - t * CONV_DIM;
    float acc = cb[c];
#pragma unroll
    for (int k = 0; k < D_CONV; ++k) {
        int tt = t - (D_CONV - 1) + k;
        if (tt >= 0) {
            float q = rintf(zx[(size_t)tt * D_IN_PROJ + D_INNER + c] * inv_s);
            q = fminf(fmaxf(q, -128.0f), 127.0f);
            acc = fmaf(q, qcw[c * D_CONV + k], acc);
        }
    }
    float v = acc * (cscale[0] * s);
    xact[i] = v / (1.0f + expf(-v));
}

// ================= chunked SSM scan =================
__global__ __launch_bounds__(256) void k_scan_local(
    const float* __restrict__ xact, const float* __restrict__ zx,
    const float* __restrict__ dtbias, const float* __restrict__ A_log,
    float* __restrict__ y, float* __restrict__ hloc, float* __restrict__ dpre) {
    const int head = blockIdx.x;
    const int seg  = blockIdx.y;
    const int tid  = threadIdx.x;
    const int p  = tid >> 2;
    const int nc = tid & 3;
    const int t0 = seg * T_SEG;

    __shared__ float4 sB4[T_SEG][32];
    __shared__ float4 sC4[T_SEG][32];
    __shared__ float  sX[T_SEG][64];
    __shared__ float  sDt[T_SEG], sA[T_SEG];

#pragma unroll
    for (int it = 0; it < 4; ++it) {
        int slot = tid + it * 256;
        int t = slot >> 5, c4 = slot & 31;
        const float* rowp = xact + (size_t)(t0 + t) * CONV_DIM + D_INNER;
        float4 bv = *(const float4*)(rowp + c4 * 4);
        float4 cv = *(const float4*)(rowp + D_STATE + c4 * 4);
        int grp = c4 >> 3, r4 = c4 & 7;
        int sl = grp * 8 + ((r4 + 2 * grp) & 7);
        sB4[t][sl] = bv;
        sC4[t][sl] = cv;
    }
#pragma unroll
    for (int it = 0; it < 2; ++it) {
        int slot = tid + it * 256;
        int t = slot >> 4, c4 = slot & 15;
        *(float4*)&sX[t][c4 * 4] =
            *(const float4*)(xact + (size_t)(t0 + t) * CONV_DIM + head * HEADDIM + c4 * 4);
    }
    if (tid < T_SEG) {
        float v = zx[(size_t)(t0 + tid) * D_IN_PROJ + (D_INNER + CONV_DIM) + head] + dtbias[head];
        float dtv = fmaxf(v, 0.f) + log1pf(expf(-fabsf(v)));
        sDt[tid] = dtv;
        sA[tid] = expf(dtv * (-expf(A_log[head])));
    }
    __syncthreads();

    float h[32];
#pragma unroll
    for (int j = 0; j < 32; ++j) h[j] = 0.f;
    float d = 1.f;
    float* yrow = y + head * HEADDIM + p;

    for (int t = 0; t < T_SEG; ++t) {
        float a = sA[t], dtv = sDt[t];
        float xdt = sX[t][p] * dtv;
        d *= a;
        float acc = 0.f;
#pragma unroll
        for (int j4 = 0; j4 < 8; ++j4) {
            int sl = nc * 8 + ((j4 + 2 * nc) & 7);
            float4 Bv = sB4[t][sl];
            float4 Cv = sC4[t][sl];
            h[j4 * 4 + 0] = fmaf(a, h[j4 * 4 + 0], xdt * Bv.x); acc = fmaf(h[j4 * 4 + 0], Cv.x, acc);
            h[j4 * 4 + 1] = fmaf(a, h[j4 * 4 + 1], xdt * Bv.y); acc = fmaf(h[j4 * 4 + 1], Cv.y, acc);
            h[j4 * 4 + 2] = fmaf(a, h[j4 * 4 + 2], xdt * Bv.z); acc = fmaf(h[j4 * 4 + 2], Cv.z, acc);
            h[j4 * 4 + 3] = fmaf(a, h[j4 * 4 + 3], xdt * Bv.w); acc = fmaf(h[j4 * 4 + 3], Cv.w, acc);
        }
        acc += __shfl_xor(acc, 1);
        acc += __shfl_xor(acc, 2);
        if (nc == 0) yrow[(size_t)(t0 + t) * D_INNER] = acc;
        if (tid == 0) dpre[(head * NSEG + seg) * T_SEG + t] = d;
    }

    float* hb = hloc + ((size_t)(head * NSEG + seg) * 64 + p) * 128 + nc * 32;
#pragma unroll
    for (int j4 = 0; j4 < 8; ++j4)
        *(float4*)(hb + j4 * 4) =
            make_float4(h[j4 * 4], h[j4 * 4 + 1], h[j4 * 4 + 2], h[j4 * 4 + 3]);
}

__global__ __launch_bounds__(256) void k_scan_seg(float* __restrict__ hloc,
                                                  const float* __restrict__ dpre) {
    int g = blockIdx.x * 256 + threadIdx.x;
    int head = g >> 11;
    int e4 = g & 2047;
    float4 run = make_float4(0.f, 0.f, 0.f, 0.f);
    for (int seg = 0; seg < NSEG; ++seg) {
        float d = dpre[(head * NSEG + seg) * T_SEG + (T_SEG - 1)];
        float4* ptr = (float4*)hloc + (size_t)(head * NSEG + seg) * 2048 + e4;
        float4 v = *ptr;
        run.x = fmaf(d, run.x, v.x);
        run.y = fmaf(d, run.y, v.y);
        run.z = fmaf(d, run.z, v.z);
        run.w = fmaf(d, run.w, v.w);
        *ptr = run;
    }
}

__global__ __launch_bounds__(256) void k_scan_fix(
    const float* __restrict__ xact, const float* __restrict__ hloc,
    const float* __restrict__ dpre, float* __restrict__ y) {
    const int head = blockIdx.x;
    const int seg  = blockIdx.y + 1;
    const int tid  = threadIdx.x;
    const int p  = tid >> 2;
    const int nc = tid & 3;
    const int t0 = seg * T_SEG;

    __shared__ float4 sC4[T_SEG][32];
    __shared__ float  sD[T_SEG];

#pragma unroll
    for (int it = 0; it < 4; ++it) {
        int slot = tid + it * 256;
        int t = slot >> 5, c4 = slot & 31;
        float4 cv = *(const float4*)(xact + (size_t)(t0 + t) * CONV_DIM + D_INNER + D_STATE + c4 * 4);
        int grp = c4 >> 3, r4 = c4 & 7;
        sC4[t][grp * 8 + ((r4 + 2 * grp) & 7)] = cv;
    }
    if (tid < T_SEG) sD[tid] = dpre[(head * NSEG + seg) * T_SEG + tid];
    __syncthreads();

    float H[32];
    const float* hb = hloc + ((size_t)(head * NSEG + seg - 1) * 64 + p) * 128 + nc * 32;
#pragma unroll
    for (int j4 = 0; j4 < 8; ++j4) {
        float4 v = *(const float4*)(hb + j4 * 4);
        H[j4 * 4 + 0] = v.x; H[j4 * 4 + 1] = v.y; H[j4 * 4 + 2] = v.z; H[j4 * 4 + 3] = v.w;
    }
    float* yrow = y + head * HEADDIM + p;
    for (int t = 0; t < T_SEG; ++t) {
        float acc = 0.f;
#pragma unroll
        for (int j4 = 0; j4 < 8; ++j4) {
            int sl = nc * 8 + ((j4 + 2 * nc) & 7);
            float4 Cv = sC4[t][sl];
            acc = fmaf(H[j4 * 4 + 0], Cv.x, acc);
            acc = fmaf(H[j4 * 4 + 1], Cv.y, acc);
            acc = fmaf(H[j4 * 4 + 2], Cv.z, acc);
            acc = fmaf(H[j4 * 4 + 3], Cv.w, acc);
        }
        acc += __shfl_xor(acc, 1);
        acc += __shfl_xor(acc, 2);
        if (nc == 0) yrow[(size_t)(t0 + t) * D_INNER] += sD[t] * acc;
    }
}

// ---------------- gate + rmsnorm(1536) -> fp32 + bf16 hi/lo ----------------
__global__ void k_gatenorm(const float* __restrict__ ybuf, const float* __restrict__ zx,
                           const float* __restrict__ xact, const float* __restrict__ dpar,
                           const float* __restrict__ mnw, float* __restrict__ y3,
                           unsigned short* __restrict__ y3h, unsigned short* __restrict__ y3l) {
    __shared__ float sbuf[256];
    int t = blockIdx.x;
    const float* yr = ybuf + (long)t * D_INNER;
    const float* zr = zx + (long)t * D_IN_PROJ;
    const float* xa = xact + (long)t * CONV_DIM;
    float vals[6];
    float ss = 0.f;
#pragma unroll
    for (int j = 0; j < 6; ++j) {
        int e = threadIdx.x + j * 256;
        float z = zr[e];
        float v = (yr[e] + xa[e] * dpar[e >> 6]) * (z / (1.0f + expf(-z)));
        vals[j] = v; ss += v * v;
    }
    sbuf[threadIdx.x] = ss; __syncthreads();
    for (int s = 128; s > 0; s >>= 1) {
        if (threadIdx.x < s) sbuf[threadIdx.x] += sbuf[threadIdx.x + s];
        __syncthreads();
    }
    float scale = 1.0f / sqrtf(sbuf[0] / (float)D_INNER + EPS);
#pragma unroll
    for (int j = 0; j < 6; ++j) {
        int e = threadIdx.x + j * 256;
        float v = vals[j] * scale * mnw[e];
        y3[(long)t * D_INNER + e] = v;
        unsigned short h = f2bf(v);
        y3h[(long)t * D_INNER + e] = h;
        y3l[(long)t * D_INNER + e] = f2bf(v - bf2f(h));
    }
}

extern "C" void kernel_launch(void* const* d_in, const int* in_sizes, int n_in,
                              void* d_out, int out_size, void* d_ws, size_t ws_size,
                              hipStream_t stream) {
    const int*   ids    = (const int*)d_in[0];
    const float* emb    = (const float*)d_in[1];
    const float* norm_w = (const float*)d_in[2];
    const float* inw    = (const float*)d_in[3];
    const float* qconv  = (const float*)d_in[4];
    const float* cscale = (const float*)d_in[5];
    const float* convb  = (const float*)d_in[6];
    const float* dtbias = (const float*)d_in[7];
    const float* alog   = (const float*)d_in[8];
    const float* dpar   = (const float*)d_in[9];
    const float* mnw    = (const float*)d_in[10];
    const float* outw   = (const float*)d_in[11];
    const float* normf  = (const float*)d_in[12];
    const float* lmw    = (const float*)d_in[13];
    float* out = (float*)d_out;

    char* base = (char*)d_ws;
    size_t off = 0;
    auto alloc = [&](size_t bytes) { char* r = base + off; off = (off + bytes + 255) & ~(size_t)255; return r; };

    float* xres = (float*)alloc((size_t)SEQLEN * D_MODEL * 4);
    float* u    = (float*)alloc((size_t)SEQLEN * D_MODEL * 4);
    float* zx   = (float*)alloc((size_t)SEQLEN * D_IN_PROJ * 4);
    float* xact = (float*)alloc((size_t)SEQLEN * CONV_DIM * 4);
    float* ybuf = (float*)alloc((size_t)SEQLEN * D_INNER * 4);
    float* y3   = (float*)alloc((size_t)SEQLEN * D_INNER * 4);
    float* hloc = (float*)alloc((size_t)NHEADS * NSEG * HEADDIM * D_STATE * 4);
    float* dpre = (float*)alloc((size_t)NHEADS * NSEG * T_SEG * 4);
    unsigned* mx = (unsigned*)alloc(64);
    unsigned short* uh  = (unsigned short*)alloc((size_t)SEQLEN * D_MODEL * 2);
    unsigned short* ul  = (unsigned short*)alloc((size_t)SEQLEN * D_MODEL * 2);
    unsigned short* y3h = (unsigned short*)alloc((size_t)SEQLEN * D_INNER * 2);
    unsigned short* y3l = (unsigned short*)alloc((size_t)SEQLEN * D_INNER * 2);
    unsigned short* lmwh = (unsigned short*)alloc((size_t)VOCAB * D_MODEL * 2);
    size_t core_need = off;
    unsigned short* inwh = (unsigned short*)alloc((size_t)N_LAYER * D_IN_PROJ * D_MODEL * 2);
    unsigned short* inwl = (unsigned short*)alloc((size_t)N_LAYER * D_IN_PROJ * D_MODEL * 2);
    unsigned short* outwh = (unsigned short*)alloc((size_t)N_LAYER * D_MODEL * D_INNER * 2);
    unsigned short* outwl = (unsigned short*)alloc((size_t)N_LAYER * D_MODEL * D_INNER * 2);
    size_t full_need = off;
    const bool big = (ws_size >= full_need);
    (void)core_need;

    k_embed<<<SEQLEN, 256, 0, stream>>>(ids, emb, xres);
    k_f2bf<<<2048, 256, 0, stream>>>(lmw, lmwh, (VOCAB * D_MODEL) / 8);
    if (big) {
        k_f2bf2<<<2048, 256, 0, stream>>>(inw, inwh, inwl, (N_LAYER * D_IN_PROJ * D_MODEL) / 8);
        k_f2bf2<<<2048, 256, 0, stream>>>(outw, outwh, outwl, (N_LAYER * D_MODEL * D_INNER) / 8);
    }

    int nq = SEQLEN * CONV_DIM;
    const int NT_IN = (D_IN_PROJ + 127) / 128;    // 27
    const int NT_LM = (VOCAB + 127) / 128;        // 393
    for (int l = 0; l < N_LAYER; ++l) {
        k_lutnorm<<<SEQLEN, 256, 0, stream>>>(xres, norm_w + l * D_MODEL, u, uh, ul);
        hipMemsetAsync(mx, 0, 4, stream);
        if (big) {
            int nblk = 8 * 8 * ((NT_IN + 7) / 8);
            k_gemm_big<3, true><<<nblk, 512, 0, stream>>>(
                uh, ul, inwh + (size_t)l * D_IN_PROJ * D_MODEL,
                inwl + (size_t)l * D_IN_PROJ * D_MODEL, zx, D_IN_PROJ, NT_IN, D_MODEL, mx);
        } else {
            dim3 g1(SEQLEN / 128, NT_IN);
            k_gemm_mfma<3, false><<<g1, 256, 0, stream>>>(u, inw + (size_t)l * D_IN_PROJ * D_MODEL,
                                                          zx, SEQLEN, D_IN_PROJ, D_MODEL);
            k_absmax<<<256, 256, 0, stream>>>(zx, mx);
        }
        k_convq<<<(nq + 255) / 256, 256, 0, stream>>>(zx, qconv + l * CONV_DIM * D_CONV,
                                                      convb + l * CONV_DIM, cscale + l, mx, xact);
        dim3 gs1(NHEADS, NSEG);
        k_scan_local<<<gs1, 256, 0, stream>>>(xact, zx, dtbias + l * NHEADS, alog + l * NHEADS,
                                              ybuf, hloc, dpre);
        k_scan_seg<<<192, 256, 0, stream>>>(hloc, dpre);
        dim3 gs3(NHEADS, NSEG - 1);
        k_scan_fix<<<gs3, 256, 0, stream>>>(xact, hloc, dpre, ybuf);
        k_gatenorm<<<SEQLEN, 256, 0, stream>>>(ybuf, zx, xact, dpar + l * NHEADS,
                                               mnw + l * D_INNER, y3, y3h, y3l);
        if (big) {
            k_gemm_out<<<256, 256, 0, stream>>>(y3h, y3l,
                outwh + (size_t)l * D_MODEL * D_INNER, outwl + (size_t)l * D_MODEL * D_INNER, xres);
        } else {
            dim3 g2(SEQLEN / 128, (D_MODEL + 127) / 128);
            k_gemm_mfma<3, true><<<g2, 256, 0, stream>>>(y3, outw + (size_t)l * D_MODEL * D_INNER,
                                                         xres, SEQLEN, D_MODEL, D_INNER);
        }
    }
    k_lutnorm<<<SEQLEN, 256, 0, stream>>>(xres, normf, u, uh, ul);
    {
        int nblk = 8 * 8 * ((NT_LM + 7) / 8);
        k_gemm_big<1, false><<<nblk, 512, 0, stream>>>(uh, nullptr, lmwh, nullptr,
                                                       out, VOCAB, NT_LM, D_MODEL, nullptr);
    }
}